// Round 1
// baseline (359.917 us; speedup 1.0000x reference)
//
#include <hip/hip_runtime.h>
#include <hip/hip_bf16.h>

#define F 128
#define HID 64
#define RPB 8   // rows (nodes) per block in node_mlp

// ---------------------------------------------------------------------------
// v1[k] = sum_j node_kernel[k][j] * attn[j]   (fold node_kernel into attn a1)
// ---------------------------------------------------------------------------
__global__ void compute_v1(const float* __restrict__ nk,
                           const float* __restrict__ attn,
                           float* __restrict__ v1) {
    int k = threadIdx.x;  // 128 threads
    float acc = 0.f;
    for (int j = 0; j < F; ++j) acc = fmaf(nk[k * F + j], attn[j], acc);
    v1[k] = acc;
}

// ---------------------------------------------------------------------------
// Per-node message MLP: M = relu(h@W1+b1)@W2+b2,  p = M·v1,  q = h·attn[F:]
// Block: 128 threads, RPB nodes per block.
// ---------------------------------------------------------------------------
__global__ __launch_bounds__(128) void node_mlp(
    const float* __restrict__ h,
    const float* __restrict__ W1, const float* __restrict__ b1,
    const float* __restrict__ W2, const float* __restrict__ b2,
    const float* __restrict__ v1, const float* __restrict__ attn,
    float* __restrict__ M, float* __restrict__ p, float* __restrict__ q,
    int n)
{
    __shared__ float hs[RPB][F];
    __shared__ float Ts[RPB][F];
    __shared__ float Ms[RPB][F];
    int tid = threadIdx.x;
    int row0 = blockIdx.x * RPB;

    for (int r = 0; r < RPB; ++r) {
        int row = row0 + r;
        hs[r][tid] = (row < n) ? h[row * F + tid] : 0.0f;
    }
    __syncthreads();

    float b1o = b1[tid];
    for (int r = 0; r < RPB; ++r) {
        float acc = b1o;
        #pragma unroll 4
        for (int k = 0; k < F; ++k) acc = fmaf(hs[r][k], W1[k * F + tid], acc);
        Ts[r][tid] = fmaxf(acc, 0.0f);
    }
    __syncthreads();

    float b2o = b2[tid];
    for (int r = 0; r < RPB; ++r) {
        float acc = b2o;
        #pragma unroll 4
        for (int k = 0; k < F; ++k) acc = fmaf(Ts[r][k], W2[k * F + tid], acc);
        Ms[r][tid] = acc;
        int row = row0 + r;
        if (row < n) M[row * F + tid] = acc;
    }
    __syncthreads();

    // p and q: 16 threads per row
    int r  = tid >> 4;
    int j0 = tid & 15;
    float accp = 0.f, accq = 0.f;
    for (int k = j0; k < F; k += 16) {
        accp = fmaf(Ms[r][k], v1[k], accp);
        accq = fmaf(hs[r][k], attn[F + k], accq);
    }
    #pragma unroll
    for (int off = 8; off >= 1; off >>= 1) {
        accp += __shfl_down(accp, off, 16);
        accq += __shfl_down(accq, off, 16);
    }
    int row = row0 + r;
    if (j0 == 0 && row < n) { p[row] = accp; q[row] = accq; }
}

// ---------------------------------------------------------------------------
// CSR build: histogram -> scan -> fill
// ---------------------------------------------------------------------------
__global__ void hist_kernel(const int* __restrict__ dst, int* counts, int e) {
    int i = blockIdx.x * blockDim.x + threadIdx.x;
    if (i < e) atomicAdd(&counts[dst[i]], 1);
}

__global__ void scan_kernel(const int* __restrict__ counts,
                            int* __restrict__ row_start,
                            int* __restrict__ cursor, int n) {
    __shared__ int buf[1024];
    __shared__ int carry;
    int tid = threadIdx.x;
    if (tid == 0) carry = 0;
    __syncthreads();
    for (int base = 0; base < n; base += 1024) {
        int i = base + tid;
        int v = (i < n) ? counts[i] : 0;
        buf[tid] = v;
        __syncthreads();
        for (int off = 1; off < 1024; off <<= 1) {
            int t = (tid >= off) ? buf[tid - off] : 0;
            __syncthreads();
            buf[tid] += t;
            __syncthreads();
        }
        int incl = buf[tid];
        int excl = incl - v;
        if (i < n) {
            int rs = carry + excl;
            row_start[i] = rs;
            cursor[i] = rs;
        }
        __syncthreads();
        if (tid == 0) carry += buf[1023];
        __syncthreads();
    }
    if (tid == 0) row_start[n] = carry;
}

__global__ void fill_kernel(const int* __restrict__ dst, int* cursor,
                            int* __restrict__ sorted, int e) {
    int i = blockIdx.x * blockDim.x + threadIdx.x;
    if (i < e) {
        int pos = atomicAdd(&cursor[dst[i]], 1);
        sorted[pos] = i;
    }
}

// ---------------------------------------------------------------------------
// Per-destination-node: segment softmax over incoming edges, weighted gather
// of M rows, feed-forward update, readout MLP. One 128-thread block per node.
// ---------------------------------------------------------------------------
__global__ __launch_bounds__(128) void agg_update_readout(
    const float* __restrict__ h, const int* __restrict__ src_idx,
    const float* __restrict__ M, const float* __restrict__ p,
    const float* __restrict__ q,
    const int* __restrict__ row_start, const int* __restrict__ sorted,
    const float* __restrict__ Wu, const float* __restrict__ bu,
    const float* __restrict__ Wr1, const float* __restrict__ br1,
    const float* __restrict__ Wr2, const float* __restrict__ br2,
    float* __restrict__ out, int n)
{
    int node = blockIdx.x;
    int tid = threadIdx.x;  // 128
    __shared__ float red[128];
    __shared__ float ws[128];
    __shared__ int   ss[128];
    __shared__ float aggs[F];
    __shared__ float hs[F];
    __shared__ float hns[F];

    int start = row_start[node];
    int end   = row_start[node + 1];
    int deg   = end - start;
    float qn  = q[node];
    float acc = 0.0f;

    if (deg > 0) {
        // phase 1: segment max of leaky_relu(p[src]+q[dst])
        float lmax = -1e30f;
        for (int i = start + tid; i < end; i += 128) {
            int e = sorted[i];
            float s = p[src_idx[e]] + qn;
            float ev = (s > 0.f) ? s : 0.2f * s;
            lmax = fmaxf(lmax, ev);
        }
        red[tid] = lmax;
        __syncthreads();
        #pragma unroll
        for (int off = 64; off >= 1; off >>= 1) {
            if (tid < off) red[tid] = fmaxf(red[tid], red[tid + off]);
            __syncthreads();
        }
        float mx = red[0];
        __syncthreads();

        // phase 2: sum of exp(e - max)
        float lsum = 0.f;
        for (int i = start + tid; i < end; i += 128) {
            int e = sorted[i];
            float s = p[src_idx[e]] + qn;
            float ev = (s > 0.f) ? s : 0.2f * s;
            lsum += __expf(ev - mx);
        }
        red[tid] = lsum;
        __syncthreads();
        #pragma unroll
        for (int off = 64; off >= 1; off >>= 1) {
            if (tid < off) red[tid] += red[tid + off];
            __syncthreads();
        }
        float inv = 1.0f / (red[0] + 1e-9f);
        __syncthreads();

        // phase 3: weighted gather of M rows, chunked through LDS
        for (int base = start; base < end; base += 128) {
            int i = base + tid;
            if (i < end) {
                int e = sorted[i];
                int sidx = src_idx[e];
                float s = p[sidx] + qn;
                float ev = (s > 0.f) ? s : 0.2f * s;
                ws[tid] = __expf(ev - mx) * inv;
                ss[tid] = sidx;
            }
            __syncthreads();
            int cnt = min(128, end - base);
            for (int j = 0; j < cnt; ++j) {
                acc = fmaf(ws[j], M[(size_t)ss[j] * F + tid], acc);
            }
            __syncthreads();
        }
    }

    // phase 4: h_new = relu(agg@Wu[:F] + h@Wu[F:] + bu)
    aggs[tid] = acc;
    hs[tid]   = h[(size_t)node * F + tid];
    __syncthreads();
    float u = bu[tid];
    #pragma unroll 4
    for (int k = 0; k < F; ++k) u = fmaf(aggs[k], Wu[k * F + tid], u);
    #pragma unroll 4
    for (int k = 0; k < F; ++k) u = fmaf(hs[k], Wu[(F + k) * F + tid], u);
    u = fmaxf(u, 0.f);
    hns[tid] = u;
    __syncthreads();

    // phase 5: readout: relu(h_new@Wr1+br1)@Wr2+br2  (wave 0 only)
    if (tid < HID) {
        float r1 = br1[tid];
        #pragma unroll 4
        for (int o = 0; o < F; ++o) r1 = fmaf(hns[o], Wr1[o * HID + tid], r1);
        r1 = fmaxf(r1, 0.f);
        float part = r1 * Wr2[tid];
        #pragma unroll
        for (int off = 32; off >= 1; off >>= 1) part += __shfl_down(part, off, 64);
        if (tid == 0) out[node] = part + br2[0];
    }
}

// ---------------------------------------------------------------------------
extern "C" void kernel_launch(void* const* d_in, const int* in_sizes, int n_in,
                              void* d_out, int out_size, void* d_ws, size_t ws_size,
                              hipStream_t stream) {
    const float* h    = (const float*)d_in[0];
    const int*   src  = (const int*)d_in[1];
    const int*   dst  = (const int*)d_in[2];
    const float* W1   = (const float*)d_in[3];
    const float* b1   = (const float*)d_in[4];
    const float* W2   = (const float*)d_in[5];
    const float* b2   = (const float*)d_in[6];
    const float* nk   = (const float*)d_in[7];
    const float* attn = (const float*)d_in[8];
    const float* Wu   = (const float*)d_in[9];
    const float* bu   = (const float*)d_in[10];
    const float* Wr1  = (const float*)d_in[11];
    const float* br1  = (const float*)d_in[12];
    const float* Wr2  = (const float*)d_in[13];
    const float* br2  = (const float*)d_in[14];
    float* out = (float*)d_out;

    int n = in_sizes[0] / F;    // 10000
    int e = in_sizes[1];        // 640000

    char* ws = (char*)d_ws;
    size_t off = 0;
    auto alloc = [&](size_t bytes) {
        void* pp = ws + off;
        off += (bytes + 511) & ~(size_t)511;
        return pp;
    };
    float* M      = (float*)alloc((size_t)n * F * 4);
    float* p      = (float*)alloc((size_t)n * 4);
    float* q      = (float*)alloc((size_t)n * 4);
    float* v1     = (float*)alloc(F * 4);
    int*   counts = (int*)alloc((size_t)n * 4);
    int*   rstart = (int*)alloc((size_t)(n + 1) * 4);
    int*   cursor = (int*)alloc((size_t)n * 4);
    int*   sorted = (int*)alloc((size_t)e * 4);

    hipMemsetAsync(counts, 0, (size_t)n * 4, stream);
    compute_v1<<<1, F, 0, stream>>>(nk, attn, v1);
    node_mlp<<<(n + RPB - 1) / RPB, 128, 0, stream>>>(h, W1, b1, W2, b2, v1,
                                                      attn, M, p, q, n);
    hist_kernel<<<(e + 255) / 256, 256, 0, stream>>>(dst, counts, e);
    scan_kernel<<<1, 1024, 0, stream>>>(counts, rstart, cursor, n);
    fill_kernel<<<(e + 255) / 256, 256, 0, stream>>>(dst, cursor, sorted, e);
    agg_update_readout<<<n, 128, 0, stream>>>(h, src, M, p, q, rstart, sorted,
                                              Wu, bu, Wr1, br1, Wr2, br2,
                                              out, n);
}

// Round 2
// 284.237 us; speedup vs baseline: 1.2663x; 1.2663x over previous
//
#include <hip/hip_runtime.h>
#include <hip/hip_bf16.h>

#define F 128
#define F2 64
#define HID 64
#define RPB 8
#define KMAX 4
#define NPB 32

__device__ __forceinline__ float rl_f(float x, int l) {
    return __int_as_float(__builtin_amdgcn_readlane(__float_as_int(x), l));
}
__device__ __forceinline__ int rl_i(int x, int l) {
    return __builtin_amdgcn_readlane(x, l);
}

// ---------------------------------------------------------------------------
// v1[k] = sum_j node_kernel[k][j] * attn[j]
// ---------------------------------------------------------------------------
__global__ void compute_v1(const float* __restrict__ nk,
                           const float* __restrict__ attn,
                           float* __restrict__ v1) {
    int k = threadIdx.x;  // 128 threads
    float acc = 0.f;
    for (int j = 0; j < F; ++j) acc = fmaf(nk[k * F + j], attn[j], acc);
    v1[k] = acc;
}

// ---------------------------------------------------------------------------
// Per-node message MLP: M = relu(h@W1+b1)@W2+b2,  p = M·v1,  q = h·attn[F:]
// k-outer register blocking: W loaded once per 8 rows, LDS via ds_read_b128.
// ---------------------------------------------------------------------------
__global__ __launch_bounds__(128) void node_mlp(
    const float* __restrict__ h,
    const float* __restrict__ W1, const float* __restrict__ b1,
    const float* __restrict__ W2, const float* __restrict__ b2,
    const float* __restrict__ v1, const float* __restrict__ attn,
    float* __restrict__ M, float* __restrict__ p, float* __restrict__ q,
    int n)
{
    __shared__ __align__(16) float hs[RPB][F];
    __shared__ __align__(16) float Ts[RPB][F];
    __shared__ __align__(16) float Ms[RPB][F];
    int tid = threadIdx.x;
    int row0 = blockIdx.x * RPB;

    #pragma unroll
    for (int r = 0; r < RPB; ++r) {
        int row = row0 + r;
        hs[r][tid] = (row < n) ? h[(size_t)row * F + tid] : 0.0f;
    }
    __syncthreads();

    float acc[RPB];
    {
        float b1o = b1[tid];
        #pragma unroll
        for (int r = 0; r < RPB; ++r) acc[r] = b1o;
    }
    for (int k = 0; k < F; k += 4) {
        float w0 = W1[(size_t)(k + 0) * F + tid];
        float w1 = W1[(size_t)(k + 1) * F + tid];
        float w2 = W1[(size_t)(k + 2) * F + tid];
        float w3 = W1[(size_t)(k + 3) * F + tid];
        #pragma unroll
        for (int r = 0; r < RPB; ++r) {
            float4 hv = *(const float4*)&hs[r][k];
            acc[r] = fmaf(hv.x, w0, acc[r]);
            acc[r] = fmaf(hv.y, w1, acc[r]);
            acc[r] = fmaf(hv.z, w2, acc[r]);
            acc[r] = fmaf(hv.w, w3, acc[r]);
        }
    }
    #pragma unroll
    for (int r = 0; r < RPB; ++r) Ts[r][tid] = fmaxf(acc[r], 0.0f);
    __syncthreads();

    {
        float b2o = b2[tid];
        #pragma unroll
        for (int r = 0; r < RPB; ++r) acc[r] = b2o;
    }
    for (int k = 0; k < F; k += 4) {
        float w0 = W2[(size_t)(k + 0) * F + tid];
        float w1 = W2[(size_t)(k + 1) * F + tid];
        float w2 = W2[(size_t)(k + 2) * F + tid];
        float w3 = W2[(size_t)(k + 3) * F + tid];
        #pragma unroll
        for (int r = 0; r < RPB; ++r) {
            float4 tv = *(const float4*)&Ts[r][k];
            acc[r] = fmaf(tv.x, w0, acc[r]);
            acc[r] = fmaf(tv.y, w1, acc[r]);
            acc[r] = fmaf(tv.z, w2, acc[r]);
            acc[r] = fmaf(tv.w, w3, acc[r]);
        }
    }
    #pragma unroll
    for (int r = 0; r < RPB; ++r) {
        Ms[r][tid] = acc[r];
        int row = row0 + r;
        if (row < n) M[(size_t)row * F + tid] = acc[r];
    }
    __syncthreads();

    // p and q: 16 threads per row
    int r  = tid >> 4;
    int j0 = tid & 15;
    float accp = 0.f, accq = 0.f;
    for (int k = j0; k < F; k += 16) {
        accp = fmaf(Ms[r][k], v1[k], accp);
        accq = fmaf(hs[r][k], attn[F + k], accq);
    }
    #pragma unroll
    for (int off = 8; off >= 1; off >>= 1) {
        accp += __shfl_down(accp, off, 16);
        accq += __shfl_down(accq, off, 16);
    }
    int row = row0 + r;
    if (j0 == 0 && row < n) { p[row] = accp; q[row] = accq; }
}

// ---------------------------------------------------------------------------
// CSR build: histogram -> hierarchical scan -> fill (stores src + p[src])
// ---------------------------------------------------------------------------
__global__ void hist_kernel(const int* __restrict__ dst, int* counts, int e) {
    int i = blockIdx.x * blockDim.x + threadIdx.x;
    if (i < e) atomicAdd(&counts[dst[i]], 1);
}

__global__ __launch_bounds__(256) void scan_block(const int* __restrict__ counts,
                                                  int* __restrict__ rstart,
                                                  int* __restrict__ bsum, int n) {
    int tid = threadIdx.x;
    int i = blockIdx.x * 256 + tid;
    int v = (i < n) ? counts[i] : 0;
    int lane = tid & 63, wv = tid >> 6;
    int x = v;
    #pragma unroll
    for (int off = 1; off < 64; off <<= 1) {
        int t = __shfl_up(x, off, 64);
        if (lane >= off) x += t;
    }
    __shared__ int wsum[4];
    if (lane == 63) wsum[wv] = x;
    __syncthreads();
    int woff = 0;
    #pragma unroll
    for (int wdx = 0; wdx < 4; ++wdx) woff += (wdx < wv) ? wsum[wdx] : 0;
    int incl = x + woff;
    if (i < n) rstart[i] = incl - v;   // partial exclusive scan
    if (tid == 255) bsum[blockIdx.x] = incl;
}

__global__ void scan_top(const int* __restrict__ bsum, int* __restrict__ boff,
                         int nb) {
    int tid = threadIdx.x;  // 64 threads, nb <= 64
    int v = (tid < nb) ? bsum[tid] : 0;
    int x = v;
    #pragma unroll
    for (int off = 1; off < 64; off <<= 1) {
        int t = __shfl_up(x, off, 64);
        if (tid >= off) x += t;
    }
    if (tid < nb) boff[tid] = x - v;
    if (tid == 63) boff[nb] = x;  // grand total
}

__global__ __launch_bounds__(256) void scan_add(int* __restrict__ rstart,
                                                const int* __restrict__ boff,
                                                int* __restrict__ cursor,
                                                int n, int nb) {
    int i = blockIdx.x * 256 + threadIdx.x;
    if (i < n) {
        int rv = rstart[i] + boff[blockIdx.x];
        rstart[i] = rv;
        cursor[i] = rv;
    }
    if (i == 0) rstart[n] = boff[nb];
}

__global__ void fill_kernel(const int* __restrict__ dst,
                            const int* __restrict__ src,
                            const float* __restrict__ p, int* cursor,
                            int* __restrict__ src_sorted,
                            float* __restrict__ pe, int e) {
    int i = blockIdx.x * blockDim.x + threadIdx.x;
    if (i < e) {
        int d = dst[i];
        int pos = atomicAdd(&cursor[d], 1);
        int s = src[i];
        src_sorted[pos] = s;
        pe[pos] = p[s];
    }
}

// ---------------------------------------------------------------------------
// One WAVE per destination node: segment softmax + weighted gather of M rows.
// No LDS, no barriers; shuffle reductions; readlane broadcast in the j-loop.
// ---------------------------------------------------------------------------
__global__ __launch_bounds__(256) void agg_softmax_gather(
    const float* __restrict__ M, const float* __restrict__ q,
    const int* __restrict__ row_start, const int* __restrict__ src_sorted,
    const float* __restrict__ pe, float* __restrict__ agg, int n)
{
    int lane = threadIdx.x & 63;
    int node = blockIdx.x * 4 + (threadIdx.x >> 6);
    if (node >= n) return;

    int start = row_start[node];
    int end   = row_start[node + 1];
    int deg   = end - start;
    float qn  = q[node];

    float w[KMAX];
    int   sidx[KMAX];
    float lmax = -1e30f;

    #pragma unroll
    for (int k = 0; k < KMAX; ++k) {
        int i = start + lane + (k << 6);
        bool valid = (i < end);
        float pv = valid ? pe[i] : 0.0f;
        int   sv = valid ? src_sorted[i] : 0;
        float sc = pv + qn;
        float ev = (sc > 0.0f) ? sc : 0.2f * sc;
        w[k] = valid ? ev : -1e30f;
        sidx[k] = sv;
        lmax = fmaxf(lmax, w[k]);
    }
    for (int i = start + (KMAX << 6) + lane; i < end; i += 64) {  // deg>256: never in practice
        float sc = pe[i] + qn;
        float ev = (sc > 0.0f) ? sc : 0.2f * sc;
        lmax = fmaxf(lmax, ev);
    }
    #pragma unroll
    for (int off = 32; off >= 1; off >>= 1)
        lmax = fmaxf(lmax, __shfl_xor(lmax, off, 64));

    float lsum = 0.0f;
    #pragma unroll
    for (int k = 0; k < KMAX; ++k) {
        float ex = (w[k] > -1e29f) ? __expf(w[k] - lmax) : 0.0f;
        w[k] = ex;
        lsum += ex;
    }
    for (int i = start + (KMAX << 6) + lane; i < end; i += 64) {
        float sc = pe[i] + qn;
        float ev = (sc > 0.0f) ? sc : 0.2f * sc;
        lsum += __expf(ev - lmax);
    }
    #pragma unroll
    for (int off = 32; off >= 1; off >>= 1)
        lsum += __shfl_xor(lsum, off, 64);
    float inv = 1.0f / (lsum + 1e-9f);

    const float2* M2 = (const float2*)M;
    float accx = 0.0f, accy = 0.0f;
    #pragma unroll
    for (int k = 0; k < KMAX; ++k) {
        int lim = deg - (k << 6);
        if (lim <= 0) break;
        lim = min(lim, 64);
        #pragma unroll 4
        for (int l = 0; l < lim; ++l) {
            float wj = rl_f(w[k], l);
            int   sj = rl_i(sidx[k], l);
            float2 mv = M2[(size_t)sj * F2 + lane];
            accx = fmaf(wj, mv.x, accx);
            accy = fmaf(wj, mv.y, accy);
        }
    }
    for (int base = start + (KMAX << 6); base < end; base += 64) {  // dead in practice
        int i = base + lane;
        float ex = 0.0f; int sv = 0;
        if (i < end) {
            float sc = pe[i] + qn;
            float ev = (sc > 0.0f) ? sc : 0.2f * sc;
            ex = __expf(ev - lmax);
            sv = src_sorted[i];
        }
        int lim = min(64, end - base);
        for (int l = 0; l < lim; ++l) {
            float wj = rl_f(ex, l);
            int   sj = rl_i(sv, l);
            float2 mv = M2[(size_t)sj * F2 + lane];
            accx = fmaf(wj, mv.x, accx);
            accy = fmaf(wj, mv.y, accy);
        }
    }

    float2* agg2 = (float2*)agg;
    agg2[(size_t)node * F2 + lane] = make_float2(accx * inv, accy * inv);
}

// ---------------------------------------------------------------------------
// Block-level update + readout: 32 nodes/block, Wu read once per 32 nodes.
// ---------------------------------------------------------------------------
__global__ __launch_bounds__(256) void update_readout(
    const float* __restrict__ agg, const float* __restrict__ h,
    const float* __restrict__ Wu, const float* __restrict__ bu,
    const float* __restrict__ Wr1, const float* __restrict__ br1,
    const float* __restrict__ Wr2, const float* __restrict__ br2,
    float* __restrict__ out, int n)
{
    __shared__ __align__(16) float x[NPB][2 * F];   // 32 KB [agg | h]
    __shared__ __align__(16) float hn[NPB][F];      // 16 KB
    int tid = threadIdx.x;
    int node0 = blockIdx.x * NPB;

    #pragma unroll
    for (int it = 0; it < 4; ++it) {
        int idx = tid * 4 + it * 1024;          // 0..4095, step covers NPB*F
        int nd = idx >> 7;
        int k  = idx & 127;
        int row = node0 + nd;
        float4 av = make_float4(0, 0, 0, 0), hv = make_float4(0, 0, 0, 0);
        if (row < n) {
            av = *(const float4*)&agg[(size_t)row * F + k];
            hv = *(const float4*)&h[(size_t)row * F + k];
        }
        *(float4*)&x[nd][k]     = av;
        *(float4*)&x[nd][F + k] = hv;
    }
    __syncthreads();

    // phase A: u[nd][j] = relu(x[nd] . Wu[:,j] + bu[j]); thread = (j, parity)
    int j = tid & 127;
    int s = tid >> 7;   // 0..1
    float acc[16];
    {
        float b = bu[j];
        #pragma unroll
        for (int r = 0; r < 16; ++r) acc[r] = b;
    }
    for (int k = 0; k < 2 * F; ++k) {
        float wv = Wu[(size_t)k * F + j];
        #pragma unroll
        for (int r = 0; r < 16; ++r)
            acc[r] = fmaf(x[s + 2 * r][k], wv, acc[r]);
    }
    #pragma unroll
    for (int r = 0; r < 16; ++r) hn[s + 2 * r][j] = fmaxf(acc[r], 0.0f);
    __syncthreads();

    // phase B: readout; thread = (hid, quarter)
    int hid = tid & 63;
    int s2  = tid >> 6;  // 0..3
    float r1[8];
    {
        float b = br1[hid];
        #pragma unroll
        for (int r = 0; r < 8; ++r) r1[r] = b;
    }
    for (int k = 0; k < F; ++k) {
        float wv = Wr1[(size_t)k * HID + hid];
        #pragma unroll
        for (int r = 0; r < 8; ++r)
            r1[r] = fmaf(hn[s2 + 4 * r][k], wv, r1[r]);
    }
    float w2v = Wr2[hid];
    float b2v = br2[0];
    #pragma unroll
    for (int r = 0; r < 8; ++r) {
        float part = fmaxf(r1[r], 0.0f) * w2v;
        #pragma unroll
        for (int off = 32; off >= 1; off >>= 1)
            part += __shfl_xor(part, off, 64);
        int row = node0 + s2 + 4 * r;
        if (hid == 0 && row < n) out[row] = part + b2v;
    }
}

// ---------------------------------------------------------------------------
extern "C" void kernel_launch(void* const* d_in, const int* in_sizes, int n_in,
                              void* d_out, int out_size, void* d_ws, size_t ws_size,
                              hipStream_t stream) {
    const float* h    = (const float*)d_in[0];
    const int*   src  = (const int*)d_in[1];
    const int*   dst  = (const int*)d_in[2];
    const float* W1   = (const float*)d_in[3];
    const float* b1   = (const float*)d_in[4];
    const float* W2   = (const float*)d_in[5];
    const float* b2   = (const float*)d_in[6];
    const float* nk   = (const float*)d_in[7];
    const float* attn = (const float*)d_in[8];
    const float* Wu   = (const float*)d_in[9];
    const float* bu   = (const float*)d_in[10];
    const float* Wr1  = (const float*)d_in[11];
    const float* br1  = (const float*)d_in[12];
    const float* Wr2  = (const float*)d_in[13];
    const float* br2  = (const float*)d_in[14];
    float* out = (float*)d_out;

    int n = in_sizes[0] / F;    // 10000
    int e = in_sizes[1];        // 640000
    int nb = (n + 255) / 256;   // scan blocks

    char* ws = (char*)d_ws;
    size_t off = 0;
    auto alloc = [&](size_t bytes) {
        void* pp = ws + off;
        off += (bytes + 511) & ~(size_t)511;
        return pp;
    };
    float* M        = (float*)alloc((size_t)n * F * 4);
    float* aggws    = (float*)alloc((size_t)n * F * 4);
    float* p        = (float*)alloc((size_t)n * 4);
    float* q        = (float*)alloc((size_t)n * 4);
    float* v1       = (float*)alloc(F * 4);
    int*   counts   = (int*)alloc((size_t)n * 4);
    int*   rstart   = (int*)alloc((size_t)(n + 1) * 4);
    int*   cursor   = (int*)alloc((size_t)n * 4);
    int*   bsum     = (int*)alloc((size_t)(nb + 1) * 4);
    int*   boff     = (int*)alloc((size_t)(nb + 1) * 4);
    int*   srcsort  = (int*)alloc((size_t)e * 4);
    float* pe       = (float*)alloc((size_t)e * 4);

    hipMemsetAsync(counts, 0, (size_t)n * 4, stream);
    hist_kernel<<<(e + 255) / 256, 256, 0, stream>>>(dst, counts, e);
    scan_block<<<nb, 256, 0, stream>>>(counts, rstart, bsum, n);
    scan_top<<<1, 64, 0, stream>>>(bsum, boff, nb);
    scan_add<<<nb, 256, 0, stream>>>(rstart, boff, cursor, n, nb);

    compute_v1<<<1, F, 0, stream>>>(nk, attn, v1);
    node_mlp<<<(n + RPB - 1) / RPB, 128, 0, stream>>>(h, W1, b1, W2, b2, v1,
                                                      attn, M, p, q, n);
    fill_kernel<<<(e + 255) / 256, 256, 0, stream>>>(dst, src, p, cursor,
                                                     srcsort, pe, e);
    agg_softmax_gather<<<(n + 3) / 4, 256, 0, stream>>>(M, q, rstart, srcsort,
                                                        pe, aggws, n);
    update_readout<<<(n + NPB - 1) / NPB, 256, 0, stream>>>(aggws, h, Wu, bu,
                                                            Wr1, br1, Wr2, br2,
                                                            out, n);
}

// Round 3
// 255.220 us; speedup vs baseline: 1.4102x; 1.1137x over previous
//
#include <hip/hip_runtime.h>
#include <hip/hip_bf16.h>

#define F 128
#define HID 64
#define RPB 8
#define KMAX 4
#define DEG_CAP 256   // KMAX * 64
#define NPB 32

// ---------------------------------------------------------------------------
// v1[k] = sum_j node_kernel[k][j] * attn[j]
// ---------------------------------------------------------------------------
__global__ void compute_v1(const float* __restrict__ nk,
                           const float* __restrict__ attn,
                           float* __restrict__ v1) {
    int k = threadIdx.x;  // 128 threads
    float acc = 0.f;
    for (int j = 0; j < F; ++j) acc = fmaf(nk[k * F + j], attn[j], acc);
    v1[k] = acc;
}

// ---------------------------------------------------------------------------
// Per-node message MLP: M = relu(h@W1+b1)@W2+b2,  p = M·v1,  q = h·attn[F:]
// ---------------------------------------------------------------------------
__global__ __launch_bounds__(128) void node_mlp(
    const float* __restrict__ h,
    const float* __restrict__ W1, const float* __restrict__ b1,
    const float* __restrict__ W2, const float* __restrict__ b2,
    const float* __restrict__ v1, const float* __restrict__ attn,
    float* __restrict__ M, float* __restrict__ p, float* __restrict__ q,
    int n)
{
    __shared__ __align__(16) float hs[RPB][F];
    __shared__ __align__(16) float Ts[RPB][F];
    __shared__ __align__(16) float Ms[RPB][F];
    int tid = threadIdx.x;
    int row0 = blockIdx.x * RPB;

    #pragma unroll
    for (int r = 0; r < RPB; ++r) {
        int row = row0 + r;
        hs[r][tid] = (row < n) ? h[(size_t)row * F + tid] : 0.0f;
    }
    __syncthreads();

    float acc[RPB];
    {
        float b1o = b1[tid];
        #pragma unroll
        for (int r = 0; r < RPB; ++r) acc[r] = b1o;
    }
    for (int k = 0; k < F; k += 4) {
        float w0 = W1[(size_t)(k + 0) * F + tid];
        float w1 = W1[(size_t)(k + 1) * F + tid];
        float w2 = W1[(size_t)(k + 2) * F + tid];
        float w3 = W1[(size_t)(k + 3) * F + tid];
        #pragma unroll
        for (int r = 0; r < RPB; ++r) {
            float4 hv = *(const float4*)&hs[r][k];
            acc[r] = fmaf(hv.x, w0, acc[r]);
            acc[r] = fmaf(hv.y, w1, acc[r]);
            acc[r] = fmaf(hv.z, w2, acc[r]);
            acc[r] = fmaf(hv.w, w3, acc[r]);
        }
    }
    #pragma unroll
    for (int r = 0; r < RPB; ++r) Ts[r][tid] = fmaxf(acc[r], 0.0f);
    __syncthreads();

    {
        float b2o = b2[tid];
        #pragma unroll
        for (int r = 0; r < RPB; ++r) acc[r] = b2o;
    }
    for (int k = 0; k < F; k += 4) {
        float w0 = W2[(size_t)(k + 0) * F + tid];
        float w1 = W2[(size_t)(k + 1) * F + tid];
        float w2 = W2[(size_t)(k + 2) * F + tid];
        float w3 = W2[(size_t)(k + 3) * F + tid];
        #pragma unroll
        for (int r = 0; r < RPB; ++r) {
            float4 tv = *(const float4*)&Ts[r][k];
            acc[r] = fmaf(tv.x, w0, acc[r]);
            acc[r] = fmaf(tv.y, w1, acc[r]);
            acc[r] = fmaf(tv.z, w2, acc[r]);
            acc[r] = fmaf(tv.w, w3, acc[r]);
        }
    }
    #pragma unroll
    for (int r = 0; r < RPB; ++r) {
        Ms[r][tid] = acc[r];
        int row = row0 + r;
        if (row < n) M[(size_t)row * F + tid] = acc[r];
    }
    __syncthreads();

    int r  = tid >> 4;
    int j0 = tid & 15;
    float accp = 0.f, accq = 0.f;
    for (int k = j0; k < F; k += 16) {
        accp = fmaf(Ms[r][k], v1[k], accp);
        accq = fmaf(hs[r][k], attn[F + k], accq);
    }
    #pragma unroll
    for (int off = 8; off >= 1; off >>= 1) {
        accp += __shfl_down(accp, off, 16);
        accq += __shfl_down(accq, off, 16);
    }
    int row = row0 + r;
    if (j0 == 0 && row < n) { p[row] = accp; q[row] = accq; }
}

// ---------------------------------------------------------------------------
// CSR build: histogram -> hierarchical scan -> fill (packed int2 {src,p})
// ---------------------------------------------------------------------------
__global__ void hist_kernel(const int* __restrict__ dst, int* counts, int e) {
    int i = blockIdx.x * blockDim.x + threadIdx.x;
    if (i < e) atomicAdd(&counts[dst[i]], 1);
}

__global__ __launch_bounds__(256) void scan_block(const int* __restrict__ counts,
                                                  int* __restrict__ rstart,
                                                  int* __restrict__ bsum, int n) {
    int tid = threadIdx.x;
    int i = blockIdx.x * 256 + tid;
    int v = (i < n) ? counts[i] : 0;
    int lane = tid & 63, wv = tid >> 6;
    int x = v;
    #pragma unroll
    for (int off = 1; off < 64; off <<= 1) {
        int t = __shfl_up(x, off, 64);
        if (lane >= off) x += t;
    }
    __shared__ int wsum[4];
    if (lane == 63) wsum[wv] = x;
    __syncthreads();
    int woff = 0;
    #pragma unroll
    for (int wdx = 0; wdx < 4; ++wdx) woff += (wdx < wv) ? wsum[wdx] : 0;
    int incl = x + woff;
    if (i < n) rstart[i] = incl - v;
    if (tid == 255) bsum[blockIdx.x] = incl;
}

__global__ void scan_top(const int* __restrict__ bsum, int* __restrict__ boff,
                         int nb) {
    int tid = threadIdx.x;  // 64 threads, nb <= 64
    int v = (tid < nb) ? bsum[tid] : 0;
    int x = v;
    #pragma unroll
    for (int off = 1; off < 64; off <<= 1) {
        int t = __shfl_up(x, off, 64);
        if (tid >= off) x += t;
    }
    if (tid < nb) boff[tid] = x - v;
    if (tid == 63) boff[nb] = x;
}

__global__ __launch_bounds__(256) void scan_add(int* __restrict__ rstart,
                                                const int* __restrict__ boff,
                                                int* __restrict__ cursor,
                                                int n, int nb) {
    int i = blockIdx.x * 256 + threadIdx.x;
    if (i < n) {
        int rv = rstart[i] + boff[blockIdx.x];
        rstart[i] = rv;
        cursor[i] = rv;
    }
    if (i == 0) rstart[n] = boff[nb];
}

__global__ void fill_kernel(const int* __restrict__ dst,
                            const int* __restrict__ src,
                            const float* __restrict__ p, int* cursor,
                            int2* __restrict__ rec, int e) {
    int i = blockIdx.x * blockDim.x + threadIdx.x;
    if (i < e) {
        int s = src[i];
        float pv = p[s];                 // 40 KB table, L1/L2-hit
        int pos = atomicAdd(&cursor[dst[i]], 1);
        rec[pos] = make_int2(s, __float_as_int(pv));
    }
}

// ---------------------------------------------------------------------------
// One WAVE per destination node. Softmax weights staged to a per-wave LDS
// slab (weight pre-scaled by 1/denom); gather processes 2 edges per wave
// (half-wave x float4 = full 512B row), 8 edges per batch for load ILP.
// ---------------------------------------------------------------------------
__global__ __launch_bounds__(256) void agg_softmax_gather(
    const float* __restrict__ M, const float* __restrict__ q,
    const int* __restrict__ row_start, const int2* __restrict__ rec,
    float* __restrict__ agg, int n)
{
    __shared__ int2 buf[4][DEG_CAP];     // 8 KB, per-wave slabs
    int lane = threadIdx.x & 63;
    int wv   = threadIdx.x >> 6;
    int node = blockIdx.x * 4 + wv;
    if (node >= n) return;

    int start = row_start[node];
    int end   = row_start[node + 1];
    int deg   = end - start;
    float qn  = q[node];

    float w[KMAX];
    int   sidx[KMAX];
    float lmax = -1e30f;

    #pragma unroll
    for (int k = 0; k < KMAX; ++k) {
        int i = start + lane + (k << 6);
        bool valid = (i < end);
        int2 r = valid ? rec[i] : make_int2(0, 0);
        float sc = __int_as_float(r.y) + qn;
        float ev = (sc > 0.0f) ? sc : 0.2f * sc;
        w[k] = valid ? ev : -1e30f;
        sidx[k] = valid ? r.x : 0;
        lmax = fmaxf(lmax, w[k]);
    }
    for (int i = start + DEG_CAP + lane; i < end; i += 64) {  // deg>256: ~never
        float sc = __int_as_float(rec[i].y) + qn;
        float ev = (sc > 0.0f) ? sc : 0.2f * sc;
        lmax = fmaxf(lmax, ev);
    }
    #pragma unroll
    for (int off = 32; off >= 1; off >>= 1)
        lmax = fmaxf(lmax, __shfl_xor(lmax, off, 64));

    float lsum = 0.0f;
    #pragma unroll
    for (int k = 0; k < KMAX; ++k) {
        float ex = (w[k] > -1e29f) ? __expf(w[k] - lmax) : 0.0f;
        w[k] = ex;
        lsum += ex;
    }
    for (int i = start + DEG_CAP + lane; i < end; i += 64) {
        float sc = __int_as_float(rec[i].y) + qn;
        float ev = (sc > 0.0f) ? sc : 0.2f * sc;
        lsum += __expf(ev - lmax);
    }
    #pragma unroll
    for (int off = 32; off >= 1; off >>= 1)
        lsum += __shfl_xor(lsum, off, 64);
    float inv = 1.0f / (lsum + 1e-9f);

    // stage {scaled weight, src} — same-wave LDS, no barrier needed
    #pragma unroll
    for (int k = 0; k < KMAX; ++k)
        buf[wv][lane + (k << 6)] = make_int2(__float_as_int(w[k] * inv), sidx[k]);

    const float4* M4 = (const float4*)M;
    int sub  = lane & 31;
    int half = lane >> 5;
    float accx = 0.f, accy = 0.f, accz = 0.f, accw = 0.f;
    int lim = min(deg, DEG_CAP);

    for (int base = 0; base < lim; base += 8) {
        int2 r0 = buf[wv][base + half + 0];
        int2 r1 = buf[wv][base + half + 2];
        int2 r2 = buf[wv][base + half + 4];
        int2 r3 = buf[wv][base + half + 6];
        float4 m0 = M4[(size_t)r0.y * 32 + sub];
        float4 m1 = M4[(size_t)r1.y * 32 + sub];
        float4 m2 = M4[(size_t)r2.y * 32 + sub];
        float4 m3 = M4[(size_t)r3.y * 32 + sub];
        float w0 = __int_as_float(r0.x), w1 = __int_as_float(r1.x);
        float w2 = __int_as_float(r2.x), w3 = __int_as_float(r3.x);
        accx = fmaf(w0, m0.x, accx); accy = fmaf(w0, m0.y, accy);
        accz = fmaf(w0, m0.z, accz); accw = fmaf(w0, m0.w, accw);
        accx = fmaf(w1, m1.x, accx); accy = fmaf(w1, m1.y, accy);
        accz = fmaf(w1, m1.z, accz); accw = fmaf(w1, m1.w, accw);
        accx = fmaf(w2, m2.x, accx); accy = fmaf(w2, m2.y, accy);
        accz = fmaf(w2, m2.z, accz); accw = fmaf(w2, m2.w, accw);
        accx = fmaf(w3, m3.x, accx); accy = fmaf(w3, m3.y, accy);
        accz = fmaf(w3, m3.z, accz); accw = fmaf(w3, m3.w, accw);
    }

    // overflow path (deg > 256): correctness-only, statistically dead
    for (int base = start + DEG_CAP; base < end; base += 64) {
        int i = base + lane;
        float ex = 0.f; int sv = 0;
        if (i < end) {
            int2 r = rec[i];
            float sc = __int_as_float(r.y) + qn;
            float ev = (sc > 0.0f) ? sc : 0.2f * sc;
            ex = __expf(ev - lmax) * inv;
            sv = r.x;
        }
        buf[wv][lane] = make_int2(__float_as_int(ex), sv);
        for (int b2 = 0; b2 < 64; b2 += 8) {
            int2 r0 = buf[wv][b2 + half + 0];
            int2 r1 = buf[wv][b2 + half + 2];
            int2 r2 = buf[wv][b2 + half + 4];
            int2 r3 = buf[wv][b2 + half + 6];
            float4 m0 = M4[(size_t)r0.y * 32 + sub];
            float4 m1 = M4[(size_t)r1.y * 32 + sub];
            float4 m2 = M4[(size_t)r2.y * 32 + sub];
            float4 m3 = M4[(size_t)r3.y * 32 + sub];
            float w0 = __int_as_float(r0.x), w1 = __int_as_float(r1.x);
            float w2 = __int_as_float(r2.x), w3 = __int_as_float(r3.x);
            accx = fmaf(w0, m0.x, accx); accy = fmaf(w0, m0.y, accy);
            accz = fmaf(w0, m0.z, accz); accw = fmaf(w0, m0.w, accw);
            accx = fmaf(w1, m1.x, accx); accy = fmaf(w1, m1.y, accy);
            accz = fmaf(w1, m1.z, accz); accw = fmaf(w1, m1.w, accw);
            accx = fmaf(w2, m2.x, accx); accy = fmaf(w2, m2.y, accy);
            accz = fmaf(w2, m2.z, accz); accw = fmaf(w2, m2.w, accw);
            accx = fmaf(w3, m3.x, accx); accy = fmaf(w3, m3.y, accy);
            accz = fmaf(w3, m3.z, accz); accw = fmaf(w3, m3.w, accw);
        }
    }

    // combine even/odd-edge halves and store
    accx += __shfl_xor(accx, 32, 64);
    accy += __shfl_xor(accy, 32, 64);
    accz += __shfl_xor(accz, 32, 64);
    accw += __shfl_xor(accw, 32, 64);
    if (half == 0) {
        ((float4*)agg)[(size_t)node * 32 + sub] =
            make_float4(accx, accy, accz, accw);
    }
}

// ---------------------------------------------------------------------------
// Block-level update + readout: 32 nodes/block, Wu read once per 32 nodes.
// ---------------------------------------------------------------------------
__global__ __launch_bounds__(256) void update_readout(
    const float* __restrict__ agg, const float* __restrict__ h,
    const float* __restrict__ Wu, const float* __restrict__ bu,
    const float* __restrict__ Wr1, const float* __restrict__ br1,
    const float* __restrict__ Wr2, const float* __restrict__ br2,
    float* __restrict__ out, int n)
{
    __shared__ __align__(16) float x[NPB][2 * F];   // 32 KB [agg | h]
    __shared__ __align__(16) float hn[NPB][F];      // 16 KB
    int tid = threadIdx.x;
    int node0 = blockIdx.x * NPB;

    #pragma unroll
    for (int it = 0; it < 4; ++it) {
        int idx = tid * 4 + it * 1024;
        int nd = idx >> 7;
        int k  = idx & 127;
        int row = node0 + nd;
        float4 av = make_float4(0, 0, 0, 0), hv = make_float4(0, 0, 0, 0);
        if (row < n) {
            av = *(const float4*)&agg[(size_t)row * F + k];
            hv = *(const float4*)&h[(size_t)row * F + k];
        }
        *(float4*)&x[nd][k]     = av;
        *(float4*)&x[nd][F + k] = hv;
    }
    __syncthreads();

    int j = tid & 127;
    int s = tid >> 7;   // 0..1
    float acc[16];
    {
        float b = bu[j];
        #pragma unroll
        for (int r = 0; r < 16; ++r) acc[r] = b;
    }
    for (int k = 0; k < 2 * F; k += 4) {
        float w0 = Wu[(size_t)(k + 0) * F + j];
        float w1 = Wu[(size_t)(k + 1) * F + j];
        float w2 = Wu[(size_t)(k + 2) * F + j];
        float w3 = Wu[(size_t)(k + 3) * F + j];
        #pragma unroll
        for (int r = 0; r < 16; ++r) {
            float4 xv = *(const float4*)&x[s + 2 * r][k];
            acc[r] = fmaf(xv.x, w0, acc[r]);
            acc[r] = fmaf(xv.y, w1, acc[r]);
            acc[r] = fmaf(xv.z, w2, acc[r]);
            acc[r] = fmaf(xv.w, w3, acc[r]);
        }
    }
    #pragma unroll
    for (int r = 0; r < 16; ++r) hn[s + 2 * r][j] = fmaxf(acc[r], 0.0f);
    __syncthreads();

    int hid = tid & 63;
    int s2  = tid >> 6;  // 0..3
    float r1[8];
    {
        float b = br1[hid];
        #pragma unroll
        for (int r = 0; r < 8; ++r) r1[r] = b;
    }
    for (int k = 0; k < F; k += 4) {
        float w0 = Wr1[(size_t)(k + 0) * HID + hid];
        float w1 = Wr1[(size_t)(k + 1) * HID + hid];
        float w2 = Wr1[(size_t)(k + 2) * HID + hid];
        float w3 = Wr1[(size_t)(k + 3) * HID + hid];
        #pragma unroll
        for (int r = 0; r < 8; ++r) {
            float4 hv = *(const float4*)&hn[s2 + 4 * r][k];
            r1[r] = fmaf(hv.x, w0, r1[r]);
            r1[r] = fmaf(hv.y, w1, r1[r]);
            r1[r] = fmaf(hv.z, w2, r1[r]);
            r1[r] = fmaf(hv.w, w3, r1[r]);
        }
    }
    float w2v = Wr2[hid];
    float b2v = br2[0];
    #pragma unroll
    for (int r = 0; r < 8; ++r) {
        float part = fmaxf(r1[r], 0.0f) * w2v;
        #pragma unroll
        for (int off = 32; off >= 1; off >>= 1)
            part += __shfl_xor(part, off, 64);
        int row = node0 + s2 + 4 * r;
        if (hid == 0 && row < n) out[row] = part + b2v;
    }
}

// ---------------------------------------------------------------------------
extern "C" void kernel_launch(void* const* d_in, const int* in_sizes, int n_in,
                              void* d_out, int out_size, void* d_ws, size_t ws_size,
                              hipStream_t stream) {
    const float* h    = (const float*)d_in[0];
    const int*   src  = (const int*)d_in[1];
    const int*   dst  = (const int*)d_in[2];
    const float* W1   = (const float*)d_in[3];
    const float* b1   = (const float*)d_in[4];
    const float* W2   = (const float*)d_in[5];
    const float* b2   = (const float*)d_in[6];
    const float* nk   = (const float*)d_in[7];
    const float* attn = (const float*)d_in[8];
    const float* Wu   = (const float*)d_in[9];
    const float* bu   = (const float*)d_in[10];
    const float* Wr1  = (const float*)d_in[11];
    const float* br1  = (const float*)d_in[12];
    const float* Wr2  = (const float*)d_in[13];
    const float* br2  = (const float*)d_in[14];
    float* out = (float*)d_out;

    int n = in_sizes[0] / F;    // 10000
    int e = in_sizes[1];        // 640000
    int nb = (n + 255) / 256;

    char* ws = (char*)d_ws;
    size_t off = 0;
    auto alloc = [&](size_t bytes) {
        void* pp = ws + off;
        off += (bytes + 511) & ~(size_t)511;
        return pp;
    };
    float* M      = (float*)alloc((size_t)n * F * 4);
    float* aggws  = (float*)alloc((size_t)n * F * 4);
    float* p      = (float*)alloc((size_t)n * 4);
    float* q      = (float*)alloc((size_t)n * 4);
    float* v1     = (float*)alloc(F * 4);
    int*   counts = (int*)alloc((size_t)n * 4);
    int*   rstart = (int*)alloc((size_t)(n + 1) * 4);
    int*   cursor = (int*)alloc((size_t)n * 4);
    int*   bsum   = (int*)alloc((size_t)(nb + 1) * 4);
    int*   boff   = (int*)alloc((size_t)(nb + 1) * 4);
    int2*  rec    = (int2*)alloc((size_t)e * 8);

    hipMemsetAsync(counts, 0, (size_t)n * 4, stream);
    hist_kernel<<<(e + 255) / 256, 256, 0, stream>>>(dst, counts, e);
    scan_block<<<nb, 256, 0, stream>>>(counts, rstart, bsum, n);
    scan_top<<<1, 64, 0, stream>>>(bsum, boff, nb);
    scan_add<<<nb, 256, 0, stream>>>(rstart, boff, cursor, n, nb);

    compute_v1<<<1, F, 0, stream>>>(nk, attn, v1);
    node_mlp<<<(n + RPB - 1) / RPB, 128, 0, stream>>>(h, W1, b1, W2, b2, v1,
                                                      attn, M, p, q, n);
    fill_kernel<<<(e + 255) / 256, 256, 0, stream>>>(dst, src, p, cursor,
                                                     rec, e);
    agg_softmax_gather<<<(n + 3) / 4, 256, 0, stream>>>(M, q, rstart, rec,
                                                        aggws, n);
    update_readout<<<(n + NPB - 1) / NPB, 256, 0, stream>>>(aggws, h, Wu, bu,
                                                            Wr1, br1, Wr2, br2,
                                                            out, n);
}

// Round 4
// 228.527 us; speedup vs baseline: 1.5749x; 1.1168x over previous
//
#include <hip/hip_runtime.h>
#include <hip/hip_bf16.h>

#define F 128
#define HID 64
#define RPB 8
#define KMAX 4
#define DEG_CAP 256   // KMAX * 64
#define NPB 8

// ---------------------------------------------------------------------------
// hist + rank: rank[i] = arrival order of edge i at its dst counter.
// Block 0 additionally computes v1[k] = sum_j nk[k][j]*attn[j].
// ---------------------------------------------------------------------------
__global__ __launch_bounds__(256) void hist_rank(
    const int* __restrict__ dst, int* counts, int* __restrict__ rank, int e,
    const float* __restrict__ nk, const float* __restrict__ attn,
    float* __restrict__ v1)
{
    int i = blockIdx.x * 256 + threadIdx.x;
    if (i < e) rank[i] = atomicAdd(&counts[dst[i]], 1);
    if (blockIdx.x == 0 && threadIdx.x < F) {
        int k = threadIdx.x;
        float acc = 0.f;
        for (int j = 0; j < F; ++j) acc = fmaf(nk[k * F + j], attn[j], acc);
        v1[k] = acc;
    }
}

// ---------------------------------------------------------------------------
// Per-node message MLP: M = relu(h@W1+b1)@W2+b2,  p = M·v1,  q = h·attn[F:]
// ---------------------------------------------------------------------------
__global__ __launch_bounds__(128) void node_mlp(
    const float* __restrict__ h,
    const float* __restrict__ W1, const float* __restrict__ b1,
    const float* __restrict__ W2, const float* __restrict__ b2,
    const float* __restrict__ v1, const float* __restrict__ attn,
    float* __restrict__ M, float* __restrict__ p, float* __restrict__ q,
    int n)
{
    __shared__ __align__(16) float hs[RPB][F];
    __shared__ __align__(16) float Ts[RPB][F];
    __shared__ __align__(16) float Ms[RPB][F];
    int tid = threadIdx.x;
    int row0 = blockIdx.x * RPB;

    #pragma unroll
    for (int r = 0; r < RPB; ++r) {
        int row = row0 + r;
        hs[r][tid] = (row < n) ? h[(size_t)row * F + tid] : 0.0f;
    }
    __syncthreads();

    float acc[RPB];
    {
        float b1o = b1[tid];
        #pragma unroll
        for (int r = 0; r < RPB; ++r) acc[r] = b1o;
    }
    for (int k = 0; k < F; k += 4) {
        float w0 = W1[(size_t)(k + 0) * F + tid];
        float w1 = W1[(size_t)(k + 1) * F + tid];
        float w2 = W1[(size_t)(k + 2) * F + tid];
        float w3 = W1[(size_t)(k + 3) * F + tid];
        #pragma unroll
        for (int r = 0; r < RPB; ++r) {
            float4 hv = *(const float4*)&hs[r][k];
            acc[r] = fmaf(hv.x, w0, acc[r]);
            acc[r] = fmaf(hv.y, w1, acc[r]);
            acc[r] = fmaf(hv.z, w2, acc[r]);
            acc[r] = fmaf(hv.w, w3, acc[r]);
        }
    }
    #pragma unroll
    for (int r = 0; r < RPB; ++r) Ts[r][tid] = fmaxf(acc[r], 0.0f);
    __syncthreads();

    {
        float b2o = b2[tid];
        #pragma unroll
        for (int r = 0; r < RPB; ++r) acc[r] = b2o;
    }
    for (int k = 0; k < F; k += 4) {
        float w0 = W2[(size_t)(k + 0) * F + tid];
        float w1 = W2[(size_t)(k + 1) * F + tid];
        float w2 = W2[(size_t)(k + 2) * F + tid];
        float w3 = W2[(size_t)(k + 3) * F + tid];
        #pragma unroll
        for (int r = 0; r < RPB; ++r) {
            float4 tv = *(const float4*)&Ts[r][k];
            acc[r] = fmaf(tv.x, w0, acc[r]);
            acc[r] = fmaf(tv.y, w1, acc[r]);
            acc[r] = fmaf(tv.z, w2, acc[r]);
            acc[r] = fmaf(tv.w, w3, acc[r]);
        }
    }
    #pragma unroll
    for (int r = 0; r < RPB; ++r) {
        Ms[r][tid] = acc[r];
        int row = row0 + r;
        if (row < n) M[(size_t)row * F + tid] = acc[r];
    }
    __syncthreads();

    int r  = tid >> 4;
    int j0 = tid & 15;
    float accp = 0.f, accq = 0.f;
    for (int k = j0; k < F; k += 16) {
        accp = fmaf(Ms[r][k], v1[k], accp);
        accq = fmaf(hs[r][k], attn[F + k], accq);
    }
    #pragma unroll
    for (int off = 8; off >= 1; off >>= 1) {
        accp += __shfl_down(accp, off, 16);
        accq += __shfl_down(accq, off, 16);
    }
    int row = row0 + r;
    if (j0 == 0 && row < n) { p[row] = accp; q[row] = accq; }
}

// ---------------------------------------------------------------------------
// Scan: per-block exclusive scan, then scan_add with inline top-level scan.
// ---------------------------------------------------------------------------
__global__ __launch_bounds__(256) void scan_block(const int* __restrict__ counts,
                                                  int* __restrict__ rstart,
                                                  int* __restrict__ bsum, int n) {
    int tid = threadIdx.x;
    int i = blockIdx.x * 256 + tid;
    int v = (i < n) ? counts[i] : 0;
    int lane = tid & 63, wv = tid >> 6;
    int x = v;
    #pragma unroll
    for (int off = 1; off < 64; off <<= 1) {
        int t = __shfl_up(x, off, 64);
        if (lane >= off) x += t;
    }
    __shared__ int wsum[4];
    if (lane == 63) wsum[wv] = x;
    __syncthreads();
    int woff = 0;
    #pragma unroll
    for (int wdx = 0; wdx < 4; ++wdx) woff += (wdx < wv) ? wsum[wdx] : 0;
    int incl = x + woff;
    if (i < n) rstart[i] = incl - v;
    if (tid == 255) bsum[blockIdx.x] = incl;
}

__global__ __launch_bounds__(256) void scan_add(int* __restrict__ rstart,
                                                const int* __restrict__ bsum,
                                                int n, int nb, int e) {
    __shared__ int s_off;
    int tid = threadIdx.x;
    if (tid < 64) {
        int v = (tid < nb) ? bsum[tid] : 0;
        int x = v;
        #pragma unroll
        for (int off = 1; off < 64; off <<= 1) {
            int t = __shfl_up(x, off, 64);
            if (tid >= off) x += t;
        }
        if (tid == (int)blockIdx.x) s_off = x - v;
    }
    __syncthreads();
    int i = blockIdx.x * 256 + tid;
    if (i < n) rstart[i] += s_off;
    if (blockIdx.x == 0 && tid == 0) rstart[n] = e;
}

// ---------------------------------------------------------------------------
// fill: atomic-free scatter — pos = rstart[dst] + rank.  One 4B scatter/edge.
// ---------------------------------------------------------------------------
__global__ __launch_bounds__(256) void fill_kernel(
    const int* __restrict__ dst, const int* __restrict__ src,
    const int* __restrict__ rank, const int* __restrict__ rstart,
    int* __restrict__ src_sorted, int e)
{
    int i = blockIdx.x * 256 + threadIdx.x;
    if (i < e) {
        int d = dst[i];
        src_sorted[rstart[d] + rank[i]] = src[i];
    }
}

// ---------------------------------------------------------------------------
// One WAVE per destination node. Softmax weights staged to a per-wave LDS
// slab (pre-scaled by 1/denom); gather: 2 edges per wave (half-wave x float4
// = full 512B row), 8 edges per batch for load ILP.
// ---------------------------------------------------------------------------
__global__ __launch_bounds__(256) void agg_softmax_gather(
    const float* __restrict__ M, const float* __restrict__ p,
    const float* __restrict__ q,
    const int* __restrict__ row_start, const int* __restrict__ src_sorted,
    float* __restrict__ agg, int n)
{
    __shared__ int2 buf[4][DEG_CAP];     // 8 KB, per-wave slabs
    int lane = threadIdx.x & 63;
    int wv   = threadIdx.x >> 6;
    int node = blockIdx.x * 4 + wv;
    if (node >= n) return;

    int start = row_start[node];
    int end   = row_start[node + 1];
    int deg   = end - start;
    float qn  = q[node];

    float w[KMAX];
    int   sidx[KMAX];
    float lmax = -1e30f;

    #pragma unroll
    for (int k = 0; k < KMAX; ++k) {
        int i = start + lane + (k << 6);
        bool valid = (i < end);
        int sv = valid ? src_sorted[i] : 0;
        float pv = valid ? p[sv] : 0.0f;
        float sc = pv + qn;
        float ev = (sc > 0.0f) ? sc : 0.2f * sc;
        w[k] = valid ? ev : -1e30f;
        sidx[k] = sv;
        lmax = fmaxf(lmax, w[k]);
    }
    for (int i = start + DEG_CAP + lane; i < end; i += 64) {  // deg>256: ~never
        float sc = p[src_sorted[i]] + qn;
        float ev = (sc > 0.0f) ? sc : 0.2f * sc;
        lmax = fmaxf(lmax, ev);
    }
    #pragma unroll
    for (int off = 32; off >= 1; off >>= 1)
        lmax = fmaxf(lmax, __shfl_xor(lmax, off, 64));

    float lsum = 0.0f;
    #pragma unroll
    for (int k = 0; k < KMAX; ++k) {
        float ex = (w[k] > -1e29f) ? __expf(w[k] - lmax) : 0.0f;
        w[k] = ex;
        lsum += ex;
    }
    for (int i = start + DEG_CAP + lane; i < end; i += 64) {
        float sc = p[src_sorted[i]] + qn;
        float ev = (sc > 0.0f) ? sc : 0.2f * sc;
        lsum += __expf(ev - lmax);
    }
    #pragma unroll
    for (int off = 32; off >= 1; off >>= 1)
        lsum += __shfl_xor(lsum, off, 64);
    float inv = 1.0f / (lsum + 1e-9f);

    #pragma unroll
    for (int k = 0; k < KMAX; ++k)
        buf[wv][lane + (k << 6)] = make_int2(__float_as_int(w[k] * inv), sidx[k]);

    const float4* M4 = (const float4*)M;
    int sub  = lane & 31;
    int half = lane >> 5;
    float accx = 0.f, accy = 0.f, accz = 0.f, accw = 0.f;
    int lim = min(deg, DEG_CAP);

    for (int base = 0; base < lim; base += 8) {
        int2 r0 = buf[wv][base + half + 0];
        int2 r1 = buf[wv][base + half + 2];
        int2 r2 = buf[wv][base + half + 4];
        int2 r3 = buf[wv][base + half + 6];
        float4 m0 = M4[(size_t)r0.y * 32 + sub];
        float4 m1 = M4[(size_t)r1.y * 32 + sub];
        float4 m2 = M4[(size_t)r2.y * 32 + sub];
        float4 m3 = M4[(size_t)r3.y * 32 + sub];
        float w0 = __int_as_float(r0.x), w1 = __int_as_float(r1.x);
        float w2 = __int_as_float(r2.x), w3 = __int_as_float(r3.x);
        accx = fmaf(w0, m0.x, accx); accy = fmaf(w0, m0.y, accy);
        accz = fmaf(w0, m0.z, accz); accw = fmaf(w0, m0.w, accw);
        accx = fmaf(w1, m1.x, accx); accy = fmaf(w1, m1.y, accy);
        accz = fmaf(w1, m1.z, accz); accw = fmaf(w1, m1.w, accw);
        accx = fmaf(w2, m2.x, accx); accy = fmaf(w2, m2.y, accy);
        accz = fmaf(w2, m2.z, accz); accw = fmaf(w2, m2.w, accw);
        accx = fmaf(w3, m3.x, accx); accy = fmaf(w3, m3.y, accy);
        accz = fmaf(w3, m3.z, accz); accw = fmaf(w3, m3.w, accw);
    }

    // overflow path (deg > 256): correctness-only, statistically dead
    for (int base = start + DEG_CAP; base < end; base += 64) {
        int i = base + lane;
        float ex = 0.f; int sv = 0;
        if (i < end) {
            sv = src_sorted[i];
            float sc = p[sv] + qn;
            float ev = (sc > 0.0f) ? sc : 0.2f * sc;
            ex = __expf(ev - lmax) * inv;
        }
        buf[wv][lane] = make_int2(__float_as_int(ex), sv);
        int cnt = min(64, end - base);
        for (int b2 = 0; b2 < cnt; b2 += 2) {
            int2 r0 = buf[wv][b2 + half];
            float4 m0 = M4[(size_t)r0.y * 32 + sub];
            float w0 = __int_as_float(r0.x);
            if (b2 + half < cnt) {
                accx = fmaf(w0, m0.x, accx); accy = fmaf(w0, m0.y, accy);
                accz = fmaf(w0, m0.z, accz); accw = fmaf(w0, m0.w, accw);
            }
        }
    }

    accx += __shfl_xor(accx, 32, 64);
    accy += __shfl_xor(accy, 32, 64);
    accz += __shfl_xor(accz, 32, 64);
    accw += __shfl_xor(accw, 32, 64);
    if (half == 0) {
        ((float4*)agg)[(size_t)node * 32 + sub] =
            make_float4(accx, accy, accz, accw);
    }
}

// ---------------------------------------------------------------------------
// Block-level update + readout: 8 nodes/block (12 KB LDS, 1250 blocks).
// ---------------------------------------------------------------------------
__global__ __launch_bounds__(256) void update_readout(
    const float* __restrict__ agg, const float* __restrict__ h,
    const float* __restrict__ Wu, const float* __restrict__ bu,
    const float* __restrict__ Wr1, const float* __restrict__ br1,
    const float* __restrict__ Wr2, const float* __restrict__ br2,
    float* __restrict__ out, int n)
{
    __shared__ __align__(16) float x[NPB][2 * F];   // 8 KB [agg | h]
    __shared__ __align__(16) float hn[NPB][F];      // 4 KB
    int tid = threadIdx.x;
    int node0 = blockIdx.x * NPB;

    #pragma unroll
    for (int it = 0; it < 2; ++it) {
        int idx4 = it * 256 + tid;      // 0..511 float4 slots
        int nd = idx4 >> 6;             // 64 float4 per x-row
        int k4 = idx4 & 63;
        int row = node0 + nd;
        float4 v = make_float4(0, 0, 0, 0);
        if (row < n) {
            if (k4 < 32) v = *(const float4*)&agg[(size_t)row * F + k4 * 4];
            else         v = *(const float4*)&h[(size_t)row * F + (k4 - 32) * 4];
        }
        *(float4*)&x[nd][k4 * 4] = v;
    }
    __syncthreads();

    int j = tid & 127;
    int s = tid >> 7;   // 0..1
    float acc[4];
    {
        float b = bu[j];
        #pragma unroll
        for (int r = 0; r < 4; ++r) acc[r] = b;
    }
    for (int k = 0; k < 2 * F; k += 4) {
        float w0 = Wu[(size_t)(k + 0) * F + j];
        float w1 = Wu[(size_t)(k + 1) * F + j];
        float w2 = Wu[(size_t)(k + 2) * F + j];
        float w3 = Wu[(size_t)(k + 3) * F + j];
        #pragma unroll
        for (int r = 0; r < 4; ++r) {
            float4 xv = *(const float4*)&x[s + 2 * r][k];
            acc[r] = fmaf(xv.x, w0, acc[r]);
            acc[r] = fmaf(xv.y, w1, acc[r]);
            acc[r] = fmaf(xv.z, w2, acc[r]);
            acc[r] = fmaf(xv.w, w3, acc[r]);
        }
    }
    #pragma unroll
    for (int r = 0; r < 4; ++r) hn[s + 2 * r][j] = fmaxf(acc[r], 0.0f);
    __syncthreads();

    int hid = tid & 63;
    int s2  = tid >> 6;  // 0..3
    float r1[2];
    {
        float b = br1[hid];
        r1[0] = b; r1[1] = b;
    }
    for (int k = 0; k < F; k += 4) {
        float w0 = Wr1[(size_t)(k + 0) * HID + hid];
        float w1 = Wr1[(size_t)(k + 1) * HID + hid];
        float w2 = Wr1[(size_t)(k + 2) * HID + hid];
        float w3 = Wr1[(size_t)(k + 3) * HID + hid];
        #pragma unroll
        for (int r = 0; r < 2; ++r) {
            float4 hv = *(const float4*)&hn[s2 + 4 * r][k];
            r1[r] = fmaf(hv.x, w0, r1[r]);
            r1[r] = fmaf(hv.y, w1, r1[r]);
            r1[r] = fmaf(hv.z, w2, r1[r]);
            r1[r] = fmaf(hv.w, w3, r1[r]);
        }
    }
    float w2v = Wr2[hid];
    float b2v = br2[0];
    #pragma unroll
    for (int r = 0; r < 2; ++r) {
        float part = fmaxf(r1[r], 0.0f) * w2v;
        #pragma unroll
        for (int off = 32; off >= 1; off >>= 1)
            part += __shfl_xor(part, off, 64);
        int row = node0 + s2 + 4 * r;
        if (hid == 0 && row < n) out[row] = part + b2v;
    }
}

// ---------------------------------------------------------------------------
extern "C" void kernel_launch(void* const* d_in, const int* in_sizes, int n_in,
                              void* d_out, int out_size, void* d_ws, size_t ws_size,
                              hipStream_t stream) {
    const float* h    = (const float*)d_in[0];
    const int*   src  = (const int*)d_in[1];
    const int*   dst  = (const int*)d_in[2];
    const float* W1   = (const float*)d_in[3];
    const float* b1   = (const float*)d_in[4];
    const float* W2   = (const float*)d_in[5];
    const float* b2   = (const float*)d_in[6];
    const float* nk   = (const float*)d_in[7];
    const float* attn = (const float*)d_in[8];
    const float* Wu   = (const float*)d_in[9];
    const float* bu   = (const float*)d_in[10];
    const float* Wr1  = (const float*)d_in[11];
    const float* br1  = (const float*)d_in[12];
    const float* Wr2  = (const float*)d_in[13];
    const float* br2  = (const float*)d_in[14];
    float* out = (float*)d_out;

    int n = in_sizes[0] / F;    // 10000
    int e = in_sizes[1];        // 640000
    int nb = (n + 255) / 256;

    char* ws = (char*)d_ws;
    size_t off = 0;
    auto alloc = [&](size_t bytes) {
        void* pp = ws + off;
        off += (bytes + 511) & ~(size_t)511;
        return pp;
    };
    float* M       = (float*)alloc((size_t)n * F * 4);
    float* aggws   = (float*)alloc((size_t)n * F * 4);
    float* p       = (float*)alloc((size_t)n * 4);
    float* q       = (float*)alloc((size_t)n * 4);
    float* v1      = (float*)alloc(F * 4);
    int*   counts  = (int*)alloc((size_t)n * 4);
    int*   rstart  = (int*)alloc((size_t)(n + 1) * 4);
    int*   bsum    = (int*)alloc((size_t)(nb + 1) * 4);
    int*   rank    = (int*)alloc((size_t)e * 4);
    int*   srcsort = (int*)alloc((size_t)e * 4);

    hipMemsetAsync(counts, 0, (size_t)n * 4, stream);
    hist_rank<<<(e + 255) / 256, 256, 0, stream>>>(dst, counts, rank, e,
                                                   nk, attn, v1);
    scan_block<<<nb, 256, 0, stream>>>(counts, rstart, bsum, n);
    scan_add<<<nb, 256, 0, stream>>>(rstart, bsum, n, nb, e);
    fill_kernel<<<(e + 255) / 256, 256, 0, stream>>>(dst, src, rank, rstart,
                                                     srcsort, e);
    node_mlp<<<(n + RPB - 1) / RPB, 128, 0, stream>>>(h, W1, b1, W2, b2, v1,
                                                      attn, M, p, q, n);
    agg_softmax_gather<<<(n + 3) / 4, 256, 0, stream>>>(M, p, q, rstart,
                                                        srcsort, aggws, n);
    update_readout<<<(n + NPB - 1) / NPB, 256, 0, stream>>>(aggws, h, Wu, bu,
                                                            Wr1, br1, Wr2, br2,
                                                            out, n);
}

// Round 5
// 222.762 us; speedup vs baseline: 1.6157x; 1.0259x over previous
//
#include <hip/hip_runtime.h>
#include <hip/hip_bf16.h>

#define F 128
#define HID 64
#define KMAX 4
#define DEG_CAP 256   // KMAX * 64
#define NT 32         // nodes per block in dense kernels

// ---------------------------------------------------------------------------
// hist + rank: rank[i] = arrival order of edge i at its dst counter.
// Block 0 additionally computes v1[k] = sum_j nk[k][j]*attn[j].
// ---------------------------------------------------------------------------
__global__ __launch_bounds__(256) void hist_rank(
    const int* __restrict__ dst, int* counts, int* __restrict__ rank, int e,
    const float* __restrict__ nk, const float* __restrict__ attn,
    float* __restrict__ v1)
{
    int i = blockIdx.x * 256 + threadIdx.x;
    if (i < e) rank[i] = atomicAdd(&counts[dst[i]], 1);
    if (blockIdx.x == 0 && threadIdx.x < F) {
        int k = threadIdx.x;
        float acc = 0.f;
        for (int j = 0; j < F; ++j) acc = fmaf(nk[k * F + j], attn[j], acc);
        v1[k] = acc;
    }
}

// ---------------------------------------------------------------------------
// Scan: per-block exclusive scan, then scan_add with inline top-level scan.
// ---------------------------------------------------------------------------
__global__ __launch_bounds__(256) void scan_block(const int* __restrict__ counts,
                                                  int* __restrict__ rstart,
                                                  int* __restrict__ bsum, int n) {
    int tid = threadIdx.x;
    int i = blockIdx.x * 256 + tid;
    int v = (i < n) ? counts[i] : 0;
    int lane = tid & 63, wv = tid >> 6;
    int x = v;
    #pragma unroll
    for (int off = 1; off < 64; off <<= 1) {
        int t = __shfl_up(x, off, 64);
        if (lane >= off) x += t;
    }
    __shared__ int wsum[4];
    if (lane == 63) wsum[wv] = x;
    __syncthreads();
    int woff = 0;
    #pragma unroll
    for (int wdx = 0; wdx < 4; ++wdx) woff += (wdx < wv) ? wsum[wdx] : 0;
    int incl = x + woff;
    if (i < n) rstart[i] = incl - v;
    if (tid == 255) bsum[blockIdx.x] = incl;
}

__global__ __launch_bounds__(256) void scan_add(int* __restrict__ rstart,
                                                const int* __restrict__ bsum,
                                                int n, int nb, int e) {
    __shared__ int s_off;
    int tid = threadIdx.x;
    if (tid < 64) {
        int v = (tid < nb) ? bsum[tid] : 0;
        int x = v;
        #pragma unroll
        for (int off = 1; off < 64; off <<= 1) {
            int t = __shfl_up(x, off, 64);
            if (tid >= off) x += t;
        }
        if (tid == (int)blockIdx.x) s_off = x - v;
    }
    __syncthreads();
    int i = blockIdx.x * 256 + tid;
    if (i < n) rstart[i] += s_off;
    if (blockIdx.x == 0 && tid == 0) rstart[n] = e;
}

// ---------------------------------------------------------------------------
// fill: atomic-free scatter — pos = rstart[dst] + rank.
// ---------------------------------------------------------------------------
__global__ __launch_bounds__(256) void fill_kernel(
    const int* __restrict__ dst, const int* __restrict__ src,
    const int* __restrict__ rank, const int* __restrict__ rstart,
    int* __restrict__ src_sorted, int e)
{
    int i = blockIdx.x * 256 + threadIdx.x;
    if (i < e) {
        int d = dst[i];
        src_sorted[rstart[d] + rank[i]] = src[i];
    }
}

// ---------------------------------------------------------------------------
// node_mlp_v2: register-tiled GEMM chain. 32 nodes/block, 256 threads.
// Thread owns 4 rows x 4 cols. Weights staged in LDS chunks of 32 k.
// Also emits p = M.v1 and q = h.attn[F:].
// ---------------------------------------------------------------------------
__global__ __launch_bounds__(256) void node_mlp_v2(
    const float* __restrict__ h,
    const float* __restrict__ W1, const float* __restrict__ b1,
    const float* __restrict__ W2, const float* __restrict__ b2,
    const float* __restrict__ v1, const float* __restrict__ attn,
    float* __restrict__ M, float* __restrict__ p, float* __restrict__ q,
    int n)
{
    __shared__ __align__(16) float hs[NT][F];   // 16 KB
    __shared__ __align__(16) float Ts[NT][F];   // 16 KB
    __shared__ __align__(16) float Wc[32][F];   // 16 KB weight chunk
    int tid = threadIdx.x;
    int row0 = blockIdx.x * NT;
    int j0 = (tid & 31) * 4;
    int r0 = (tid >> 5) * 4;

    // load h tile (coalesced float4)
    #pragma unroll
    for (int it = 0; it < 4; ++it) {
        int s4 = tid + it * 256;          // 1024 float4 slots
        int r = s4 >> 5, c4 = s4 & 31;
        int row = row0 + r;
        float4 v = make_float4(0, 0, 0, 0);
        if (row < n) v = *(const float4*)&h[(size_t)row * F + c4 * 4];
        *(float4*)&hs[r][c4 * 4] = v;
    }
    __syncthreads();

    // q = h . attn[F:]  (thread = row(tid>>3) x kpart(tid&7))
    {
        int r = tid >> 3, kp = tid & 7;
        float qa = 0.f;
        #pragma unroll
        for (int c = 0; c < 4; ++c) {
            float4 hv = *(const float4*)&hs[r][kp * 16 + c * 4];
            float4 av = *(const float4*)&attn[F + kp * 16 + c * 4];
            qa = fmaf(hv.x, av.x, qa); qa = fmaf(hv.y, av.y, qa);
            qa = fmaf(hv.z, av.z, qa); qa = fmaf(hv.w, av.w, qa);
        }
        #pragma unroll
        for (int off = 1; off < 8; off <<= 1) qa += __shfl_xor(qa, off, 64);
        int row = row0 + r;
        if (kp == 0 && row < n) q[row] = qa;
    }

    float4 acc[4];
    // ----- layer 1: T = relu(h @ W1 + b1) -----
    {
        float4 bv = *(const float4*)&b1[j0];
        #pragma unroll
        for (int i = 0; i < 4; ++i) acc[i] = bv;
    }
    for (int cc = 0; cc < 4; ++cc) {
        int kc = ((cc + (int)blockIdx.x) & 3) * 32;
        __syncthreads();
        #pragma unroll
        for (int it = 0; it < 4; ++it) {
            int s4 = tid + it * 256;
            int wr = s4 >> 5, wc4 = s4 & 31;
            *(float4*)&Wc[wr][wc4 * 4] =
                *(const float4*)&W1[(size_t)(kc + wr) * F + wc4 * 4];
        }
        __syncthreads();
        #pragma unroll
        for (int k4 = 0; k4 < 8; ++k4) {
            int kk = k4 * 4;
            float4 a0 = *(const float4*)&hs[r0 + 0][kc + kk];
            float4 a1 = *(const float4*)&hs[r0 + 1][kc + kk];
            float4 a2 = *(const float4*)&hs[r0 + 2][kc + kk];
            float4 a3 = *(const float4*)&hs[r0 + 3][kc + kk];
            #pragma unroll
            for (int k = 0; k < 4; ++k) {
                float4 b = *(const float4*)&Wc[kk + k][j0];
                float av0 = k == 0 ? a0.x : k == 1 ? a0.y : k == 2 ? a0.z : a0.w;
                float av1 = k == 0 ? a1.x : k == 1 ? a1.y : k == 2 ? a1.z : a1.w;
                float av2 = k == 0 ? a2.x : k == 1 ? a2.y : k == 2 ? a2.z : a2.w;
                float av3 = k == 0 ? a3.x : k == 1 ? a3.y : k == 2 ? a3.z : a3.w;
                acc[0].x = fmaf(av0, b.x, acc[0].x); acc[0].y = fmaf(av0, b.y, acc[0].y);
                acc[0].z = fmaf(av0, b.z, acc[0].z); acc[0].w = fmaf(av0, b.w, acc[0].w);
                acc[1].x = fmaf(av1, b.x, acc[1].x); acc[1].y = fmaf(av1, b.y, acc[1].y);
                acc[1].z = fmaf(av1, b.z, acc[1].z); acc[1].w = fmaf(av1, b.w, acc[1].w);
                acc[2].x = fmaf(av2, b.x, acc[2].x); acc[2].y = fmaf(av2, b.y, acc[2].y);
                acc[2].z = fmaf(av2, b.z, acc[2].z); acc[2].w = fmaf(av2, b.w, acc[2].w);
                acc[3].x = fmaf(av3, b.x, acc[3].x); acc[3].y = fmaf(av3, b.y, acc[3].y);
                acc[3].z = fmaf(av3, b.z, acc[3].z); acc[3].w = fmaf(av3, b.w, acc[3].w);
            }
        }
    }
    __syncthreads();
    #pragma unroll
    for (int i = 0; i < 4; ++i) {
        float4 t = acc[i];
        t.x = fmaxf(t.x, 0.f); t.y = fmaxf(t.y, 0.f);
        t.z = fmaxf(t.z, 0.f); t.w = fmaxf(t.w, 0.f);
        *(float4*)&Ts[r0 + i][j0] = t;
    }

    // ----- layer 2: M = T @ W2 + b2 -----
    {
        float4 bv = *(const float4*)&b2[j0];
        #pragma unroll
        for (int i = 0; i < 4; ++i) acc[i] = bv;
    }
    for (int cc = 0; cc < 4; ++cc) {
        int kc = ((cc + (int)blockIdx.x) & 3) * 32;
        __syncthreads();
        #pragma unroll
        for (int it = 0; it < 4; ++it) {
            int s4 = tid + it * 256;
            int wr = s4 >> 5, wc4 = s4 & 31;
            *(float4*)&Wc[wr][wc4 * 4] =
                *(const float4*)&W2[(size_t)(kc + wr) * F + wc4 * 4];
        }
        __syncthreads();
        #pragma unroll
        for (int k4 = 0; k4 < 8; ++k4) {
            int kk = k4 * 4;
            float4 a0 = *(const float4*)&Ts[r0 + 0][kc + kk];
            float4 a1 = *(const float4*)&Ts[r0 + 1][kc + kk];
            float4 a2 = *(const float4*)&Ts[r0 + 2][kc + kk];
            float4 a3 = *(const float4*)&Ts[r0 + 3][kc + kk];
            #pragma unroll
            for (int k = 0; k < 4; ++k) {
                float4 b = *(const float4*)&Wc[kk + k][j0];
                float av0 = k == 0 ? a0.x : k == 1 ? a0.y : k == 2 ? a0.z : a0.w;
                float av1 = k == 0 ? a1.x : k == 1 ? a1.y : k == 2 ? a1.z : a1.w;
                float av2 = k == 0 ? a2.x : k == 1 ? a2.y : k == 2 ? a2.z : a2.w;
                float av3 = k == 0 ? a3.x : k == 1 ? a3.y : k == 2 ? a3.z : a3.w;
                acc[0].x = fmaf(av0, b.x, acc[0].x); acc[0].y = fmaf(av0, b.y, acc[0].y);
                acc[0].z = fmaf(av0, b.z, acc[0].z); acc[0].w = fmaf(av0, b.w, acc[0].w);
                acc[1].x = fmaf(av1, b.x, acc[1].x); acc[1].y = fmaf(av1, b.y, acc[1].y);
                acc[1].z = fmaf(av1, b.z, acc[1].z); acc[1].w = fmaf(av1, b.w, acc[1].w);
                acc[2].x = fmaf(av2, b.x, acc[2].x); acc[2].y = fmaf(av2, b.y, acc[2].y);
                acc[2].z = fmaf(av2, b.z, acc[2].z); acc[2].w = fmaf(av2, b.w, acc[2].w);
                acc[3].x = fmaf(av3, b.x, acc[3].x); acc[3].y = fmaf(av3, b.y, acc[3].y);
                acc[3].z = fmaf(av3, b.z, acc[3].z); acc[3].w = fmaf(av3, b.w, acc[3].w);
            }
        }
    }

    // store M + p = M.v1
    float4 v1v = *(const float4*)&v1[j0];
    #pragma unroll
    for (int i = 0; i < 4; ++i) {
        int row = row0 + r0 + i;
        if (row < n) *(float4*)&M[(size_t)row * F + j0] = acc[i];
        float pp = acc[i].x * v1v.x + acc[i].y * v1v.y +
                   acc[i].z * v1v.z + acc[i].w * v1v.w;
        #pragma unroll
        for (int off = 1; off < 32; off <<= 1) pp += __shfl_xor(pp, off, 64);
        if ((tid & 31) == 0 && row < n) p[row] = pp;
    }
}

// ---------------------------------------------------------------------------
// One WAVE per destination node: segment softmax + weighted gather of M rows.
// ---------------------------------------------------------------------------
__global__ __launch_bounds__(256) void agg_softmax_gather(
    const float* __restrict__ M, const float* __restrict__ p,
    const float* __restrict__ q,
    const int* __restrict__ row_start, const int* __restrict__ src_sorted,
    float* __restrict__ agg, int n)
{
    __shared__ int2 buf[4][DEG_CAP];     // 8 KB, per-wave slabs
    int lane = threadIdx.x & 63;
    int wv   = threadIdx.x >> 6;
    int node = blockIdx.x * 4 + wv;
    if (node >= n) return;

    int start = row_start[node];
    int end   = row_start[node + 1];
    int deg   = end - start;
    float qn  = q[node];

    float w[KMAX];
    int   sidx[KMAX];
    float lmax = -1e30f;

    #pragma unroll
    for (int k = 0; k < KMAX; ++k) {
        int i = start + lane + (k << 6);
        bool valid = (i < end);
        int sv = valid ? src_sorted[i] : 0;
        float pv = valid ? p[sv] : 0.0f;
        float sc = pv + qn;
        float ev = (sc > 0.0f) ? sc : 0.2f * sc;
        w[k] = valid ? ev : -1e30f;
        sidx[k] = sv;
        lmax = fmaxf(lmax, w[k]);
    }
    for (int i = start + DEG_CAP + lane; i < end; i += 64) {
        float sc = p[src_sorted[i]] + qn;
        float ev = (sc > 0.0f) ? sc : 0.2f * sc;
        lmax = fmaxf(lmax, ev);
    }
    #pragma unroll
    for (int off = 32; off >= 1; off >>= 1)
        lmax = fmaxf(lmax, __shfl_xor(lmax, off, 64));

    float lsum = 0.0f;
    #pragma unroll
    for (int k = 0; k < KMAX; ++k) {
        float ex = (w[k] > -1e29f) ? __expf(w[k] - lmax) : 0.0f;
        w[k] = ex;
        lsum += ex;
    }
    for (int i = start + DEG_CAP + lane; i < end; i += 64) {
        float sc = p[src_sorted[i]] + qn;
        float ev = (sc > 0.0f) ? sc : 0.2f * sc;
        lsum += __expf(ev - lmax);
    }
    #pragma unroll
    for (int off = 32; off >= 1; off >>= 1)
        lsum += __shfl_xor(lsum, off, 64);
    float inv = 1.0f / (lsum + 1e-9f);

    #pragma unroll
    for (int k = 0; k < KMAX; ++k)
        buf[wv][lane + (k << 6)] = make_int2(__float_as_int(w[k] * inv), sidx[k]);

    const float4* M4 = (const float4*)M;
    int sub  = lane & 31;
    int half = lane >> 5;
    float accx = 0.f, accy = 0.f, accz = 0.f, accw = 0.f;
    int lim = min(deg, DEG_CAP);

    for (int base = 0; base < lim; base += 8) {
        int2 r0 = buf[wv][base + half + 0];
        int2 r1 = buf[wv][base + half + 2];
        int2 r2 = buf[wv][base + half + 4];
        int2 r3 = buf[wv][base + half + 6];
        float4 m0 = M4[(size_t)r0.y * 32 + sub];
        float4 m1 = M4[(size_t)r1.y * 32 + sub];
        float4 m2 = M4[(size_t)r2.y * 32 + sub];
        float4 m3 = M4[(size_t)r3.y * 32 + sub];
        float w0 = __int_as_float(r0.x), w1 = __int_as_float(r1.x);
        float w2 = __int_as_float(r2.x), w3 = __int_as_float(r3.x);
        accx = fmaf(w0, m0.x, accx); accy = fmaf(w0, m0.y, accy);
        accz = fmaf(w0, m0.z, accz); accw = fmaf(w0, m0.w, accw);
        accx = fmaf(w1, m1.x, accx); accy = fmaf(w1, m1.y, accy);
        accz = fmaf(w1, m1.z, accz); accw = fmaf(w1, m1.w, accw);
        accx = fmaf(w2, m2.x, accx); accy = fmaf(w2, m2.y, accy);
        accz = fmaf(w2, m2.z, accz); accw = fmaf(w2, m2.w, accw);
        accx = fmaf(w3, m3.x, accx); accy = fmaf(w3, m3.y, accy);
        accz = fmaf(w3, m3.z, accz); accw = fmaf(w3, m3.w, accw);
    }

    // overflow path (deg > 256): correctness-only
    for (int base = start + DEG_CAP; base < end; base += 64) {
        int i = base + lane;
        float ex = 0.f; int sv = 0;
        if (i < end) {
            sv = src_sorted[i];
            float sc = p[sv] + qn;
            float ev = (sc > 0.0f) ? sc : 0.2f * sc;
            ex = __expf(ev - lmax) * inv;
        }
        buf[wv][lane] = make_int2(__float_as_int(ex), sv);
        int cnt = min(64, end - base);
        for (int b2 = 0; b2 < cnt; b2 += 2) {
            int2 r0 = buf[wv][b2 + half];
            float4 m0 = M4[(size_t)r0.y * 32 + sub];
            float w0 = __int_as_float(r0.x);
            if (b2 + half < cnt) {
                accx = fmaf(w0, m0.x, accx); accy = fmaf(w0, m0.y, accy);
                accz = fmaf(w0, m0.z, accz); accw = fmaf(w0, m0.w, accw);
            }
        }
    }

    accx += __shfl_xor(accx, 32, 64);
    accy += __shfl_xor(accy, 32, 64);
    accz += __shfl_xor(accz, 32, 64);
    accw += __shfl_xor(accw, 32, 64);
    if (half == 0) {
        ((float4*)agg)[(size_t)node * 32 + sub] =
            make_float4(accx, accy, accz, accw);
    }
}

// ---------------------------------------------------------------------------
// update_readout_v2: register-tiled. 32 nodes/block.
// Phase A: hn = relu([agg|h] @ Wu + bu)  (K=256, LDS weight chunks)
// Phase B: out = relu(hn @ Wr1 + br1) @ Wr2 + br2
// ---------------------------------------------------------------------------
__global__ __launch_bounds__(256) void update_readout_v2(
    const float* __restrict__ agg, const float* __restrict__ h,
    const float* __restrict__ Wu, const float* __restrict__ bu,
    const float* __restrict__ Wr1, const float* __restrict__ br1,
    const float* __restrict__ Wr2, const float* __restrict__ br2,
    float* __restrict__ out, int n)
{
    __shared__ __align__(16) float X[NT][2 * F];  // 32 KB [agg|h]
    __shared__ __align__(16) float hn[NT][F];     // 16 KB
    __shared__ __align__(16) float Wc[32][F];     // 16 KB (also Wr1 chunks [64][64])
    int tid = threadIdx.x;
    int row0 = blockIdx.x * NT;
    int j0 = (tid & 31) * 4;
    int r0 = (tid >> 5) * 4;

    #pragma unroll
    for (int it = 0; it < 8; ++it) {
        int s4 = tid + it * 256;          // 2048 float4 slots
        int r = s4 >> 6, c4 = s4 & 63;
        int row = row0 + r;
        float4 v = make_float4(0, 0, 0, 0);
        if (row < n) {
            if (c4 < 32) v = *(const float4*)&agg[(size_t)row * F + c4 * 4];
            else         v = *(const float4*)&h[(size_t)row * F + (c4 - 32) * 4];
        }
        *(float4*)&X[r][c4 * 4] = v;
    }

    float4 acc[4];
    {
        float4 bv = *(const float4*)&bu[j0];
        #pragma unroll
        for (int i = 0; i < 4; ++i) acc[i] = bv;
    }
    for (int cc = 0; cc < 8; ++cc) {
        int kc = ((cc + (int)blockIdx.x) & 7) * 32;
        __syncthreads();
        #pragma unroll
        for (int it = 0; it < 4; ++it) {
            int s4 = tid + it * 256;
            int wr = s4 >> 5, wc4 = s4 & 31;
            *(float4*)&Wc[wr][wc4 * 4] =
                *(const float4*)&Wu[(size_t)(kc + wr) * F + wc4 * 4];
        }
        __syncthreads();
        #pragma unroll
        for (int k4 = 0; k4 < 8; ++k4) {
            int kk = k4 * 4;
            float4 a0 = *(const float4*)&X[r0 + 0][kc + kk];
            float4 a1 = *(const float4*)&X[r0 + 1][kc + kk];
            float4 a2 = *(const float4*)&X[r0 + 2][kc + kk];
            float4 a3 = *(const float4*)&X[r0 + 3][kc + kk];
            #pragma unroll
            for (int k = 0; k < 4; ++k) {
                float4 b = *(const float4*)&Wc[kk + k][j0];
                float av0 = k == 0 ? a0.x : k == 1 ? a0.y : k == 2 ? a0.z : a0.w;
                float av1 = k == 0 ? a1.x : k == 1 ? a1.y : k == 2 ? a1.z : a1.w;
                float av2 = k == 0 ? a2.x : k == 1 ? a2.y : k == 2 ? a2.z : a2.w;
                float av3 = k == 0 ? a3.x : k == 1 ? a3.y : k == 2 ? a3.z : a3.w;
                acc[0].x = fmaf(av0, b.x, acc[0].x); acc[0].y = fmaf(av0, b.y, acc[0].y);
                acc[0].z = fmaf(av0, b.z, acc[0].z); acc[0].w = fmaf(av0, b.w, acc[0].w);
                acc[1].x = fmaf(av1, b.x, acc[1].x); acc[1].y = fmaf(av1, b.y, acc[1].y);
                acc[1].z = fmaf(av1, b.z, acc[1].z); acc[1].w = fmaf(av1, b.w, acc[1].w);
                acc[2].x = fmaf(av2, b.x, acc[2].x); acc[2].y = fmaf(av2, b.y, acc[2].y);
                acc[2].z = fmaf(av2, b.z, acc[2].z); acc[2].w = fmaf(av2, b.w, acc[2].w);
                acc[3].x = fmaf(av3, b.x, acc[3].x); acc[3].y = fmaf(av3, b.y, acc[3].y);
                acc[3].z = fmaf(av3, b.z, acc[3].z); acc[3].w = fmaf(av3, b.w, acc[3].w);
            }
        }
    }
    __syncthreads();
    #pragma unroll
    for (int i = 0; i < 4; ++i) {
        float4 t = acc[i];
        t.x = fmaxf(t.x, 0.f); t.y = fmaxf(t.y, 0.f);
        t.z = fmaxf(t.z, 0.f); t.w = fmaxf(t.w, 0.f);
        *(float4*)&hn[r0 + i][j0] = t;
    }

    // Phase B: r1[32 rows][64 hid]; thread = 4 rows x 2 hid (h0)
    int h0 = (tid & 31) * 2;
    float r1[4][2];
    {
        float b0 = br1[h0], b1v = br1[h0 + 1];
        #pragma unroll
        for (int i = 0; i < 4; ++i) { r1[i][0] = b0; r1[i][1] = b1v; }
    }
    float* Wcr = &Wc[0][0];   // reuse as [64][64] chunk
    for (int cc = 0; cc < 2; ++cc) {
        int kc = cc * 64;
        __syncthreads();
        #pragma unroll
        for (int it = 0; it < 4; ++it) {
            int s4 = tid + it * 256;          // 1024 float4 slots = [64][16]
            int wr = s4 >> 4, wc4 = s4 & 15;
            *(float4*)&Wcr[wr * 64 + wc4 * 4] =
                *(const float4*)&Wr1[(size_t)(kc + wr) * HID + wc4 * 4];
        }
        __syncthreads();
        #pragma unroll
        for (int k4 = 0; k4 < 16; ++k4) {
            int kk = k4 * 4;
            float4 a0 = *(const float4*)&hn[r0 + 0][kc + kk];
            float4 a1 = *(const float4*)&hn[r0 + 1][kc + kk];
            float4 a2 = *(const float4*)&hn[r0 + 2][kc + kk];
            float4 a3 = *(const float4*)&hn[r0 + 3][kc + kk];
            #pragma unroll
            for (int k = 0; k < 4; ++k) {
                float2 b = *(const float2*)&Wcr[(kk + k) * 64 + h0];
                float av0 = k == 0 ? a0.x : k == 1 ? a0.y : k == 2 ? a0.z : a0.w;
                float av1 = k == 0 ? a1.x : k == 1 ? a1.y : k == 2 ? a1.z : a1.w;
                float av2 = k == 0 ? a2.x : k == 1 ? a2.y : k == 2 ? a2.z : a2.w;
                float av3 = k == 0 ? a3.x : k == 1 ? a3.y : k == 2 ? a3.z : a3.w;
                r1[0][0] = fmaf(av0, b.x, r1[0][0]); r1[0][1] = fmaf(av0, b.y, r1[0][1]);
                r1[1][0] = fmaf(av1, b.x, r1[1][0]); r1[1][1] = fmaf(av1, b.y, r1[1][1]);
                r1[2][0] = fmaf(av2, b.x, r1[2][0]); r1[2][1] = fmaf(av2, b.y, r1[2][1]);
                r1[3][0] = fmaf(av3, b.x, r1[3][0]); r1[3][1] = fmaf(av3, b.y, r1[3][1]);
            }
        }
    }

    float wa = Wr2[h0], wb = Wr2[h0 + 1];
    float b2v = br2[0];
    #pragma unroll
    for (int i = 0; i < 4; ++i) {
        float s = fmaxf(r1[i][0], 0.f) * wa + fmaxf(r1[i][1], 0.f) * wb;
        #pragma unroll
        for (int off = 1; off < 32; off <<= 1) s += __shfl_xor(s, off, 64);
        int row = row0 + r0 + i;
        if ((tid & 31) == 0 && row < n) out[row] = s + b2v;
    }
}

// ---------------------------------------------------------------------------
extern "C" void kernel_launch(void* const* d_in, const int* in_sizes, int n_in,
                              void* d_out, int out_size, void* d_ws, size_t ws_size,
                              hipStream_t stream) {
    const float* h    = (const float*)d_in[0];
    const int*   src  = (const int*)d_in[1];
    const int*   dst  = (const int*)d_in[2];
    const float* W1   = (const float*)d_in[3];
    const float* b1   = (const float*)d_in[4];
    const float* W2   = (const float*)d_in[5];
    const float* b2   = (const float*)d_in[6];
    const float* nk   = (const float*)d_in[7];
    const float* attn = (const float*)d_in[8];
    const float* Wu   = (const float*)d_in[9];
    const float* bu   = (const float*)d_in[10];
    const float* Wr1  = (const float*)d_in[11];
    const float* br1  = (const float*)d_in[12];
    const float* Wr2  = (const float*)d_in[13];
    const float* br2  = (const float*)d_in[14];
    float* out = (float*)d_out;

    int n = in_sizes[0] / F;    // 10000
    int e = in_sizes[1];        // 640000
    int nb = (n + 255) / 256;

    char* ws = (char*)d_ws;
    size_t off = 0;
    auto alloc = [&](size_t bytes) {
        void* pp = ws + off;
        off += (bytes + 511) & ~(size_t)511;
        return pp;
    };
    float* M       = (float*)alloc((size_t)n * F * 4);
    float* aggws   = (float*)alloc((size_t)n * F * 4);
    float* p       = (float*)alloc((size_t)n * 4);
    float* q       = (float*)alloc((size_t)n * 4);
    float* v1      = (float*)alloc(F * 4);
    int*   counts  = (int*)alloc((size_t)n * 4);
    int*   rstart  = (int*)alloc((size_t)(n + 1) * 4);
    int*   bsum    = (int*)alloc((size_t)(nb + 1) * 4);
    int*   rank    = (int*)alloc((size_t)e * 4);
    int*   srcsort = (int*)alloc((size_t)e * 4);

    hipMemsetAsync(counts, 0, (size_t)n * 4, stream);
    hist_rank<<<(e + 255) / 256, 256, 0, stream>>>(dst, counts, rank, e,
                                                   nk, attn, v1);
    scan_block<<<nb, 256, 0, stream>>>(counts, rstart, bsum, n);
    scan_add<<<nb, 256, 0, stream>>>(rstart, bsum, n, nb, e);
    fill_kernel<<<(e + 255) / 256, 256, 0, stream>>>(dst, src, rank, rstart,
                                                     srcsort, e);
    node_mlp_v2<<<(n + NT - 1) / NT, 256, 0, stream>>>(h, W1, b1, W2, b2, v1,
                                                       attn, M, p, q, n);
    agg_softmax_gather<<<(n + 3) / 4, 256, 0, stream>>>(M, p, q, rstart,
                                                        srcsort, aggws, n);
    update_readout_v2<<<(n + NT - 1) / NT, 256, 0, stream>>>(aggws, h, Wu, bu,
                                                             Wr1, br1, Wr2, br2,
                                                             out, n);
}

// Round 6
// 212.173 us; speedup vs baseline: 1.6963x; 1.0499x over previous
//
#include <hip/hip_runtime.h>
#include <hip/hip_bf16.h>

#define F 128
#define HID 64
#define KMAX 4
#define DEG_CAP 256   // KMAX * 64
#define NT 32         // nodes per block in dense kernels
#define REP 8         // histogram replicas

// ---------------------------------------------------------------------------
// hist + rank with 8-way replicated counters (kills same-line atomic
// serialization). Block 0 additionally computes v1 = node_kernel @ attn[:F].
// ---------------------------------------------------------------------------
__global__ __launch_bounds__(256) void hist_rank(
    const int* __restrict__ dst, int* cnt, int* __restrict__ rank, int e,
    int n, const float* __restrict__ nk, const float* __restrict__ attn,
    float* __restrict__ v1)
{
    int i = blockIdx.x * 256 + threadIdx.x;
    int rep = blockIdx.x & (REP - 1);
    if (i < e) rank[i] = atomicAdd(&cnt[rep * n + dst[i]], 1);
    if (blockIdx.x == 0 && threadIdx.x < F) {
        int k = threadIdx.x;
        float acc = 0.f;
        for (int j = 0; j < F; ++j) acc = fmaf(nk[k * F + j], attn[j], acc);
        v1[k] = acc;
    }
}

// ---------------------------------------------------------------------------
// scan_block: replica fold (repoff) + per-block exclusive scan of totals.
// rstart stays PARTIAL; consumers add the top-level offset from bsum inline.
// ---------------------------------------------------------------------------
__global__ __launch_bounds__(256) void scan_block(
    const int* __restrict__ cnt, int* __restrict__ repoff,
    int* __restrict__ rstart, int* __restrict__ bsum, int n)
{
    int tid = threadIdx.x;
    int i = blockIdx.x * 256 + tid;
    int v = 0;
    if (i < n) {
        int run = 0;
        #pragma unroll
        for (int r = 0; r < REP; ++r) {
            int c = cnt[r * n + i];
            repoff[r * n + i] = run;
            run += c;
        }
        v = run;
    }
    int lane = tid & 63, wv = tid >> 6;
    int x = v;
    #pragma unroll
    for (int off = 1; off < 64; off <<= 1) {
        int t = __shfl_up(x, off, 64);
        if (lane >= off) x += t;
    }
    __shared__ int wsum[4];
    if (lane == 63) wsum[wv] = x;
    __syncthreads();
    int woff = 0;
    #pragma unroll
    for (int wdx = 0; wdx < 4; ++wdx) woff += (wdx < wv) ? wsum[wdx] : 0;
    int incl = x + woff;
    if (i < n) rstart[i] = incl - v;
    if (tid == 255) bsum[blockIdx.x] = incl;
}

// ---------------------------------------------------------------------------
// fill: atomic-free scatter; top-level bsum scan recomputed inline in LDS.
// pos = rstart_partial[d] + boff[d>>8] + repoff[rep][d] + rank[i]
// ---------------------------------------------------------------------------
__global__ __launch_bounds__(256) void fill_kernel(
    const int* __restrict__ dst, const int* __restrict__ src,
    const int* __restrict__ rank, const int* __restrict__ rstart,
    const int* __restrict__ repoff, const int* __restrict__ bsum,
    int* __restrict__ src_sorted, int n, int nb, int e)
{
    __shared__ int sbo[64];
    int tid = threadIdx.x;
    if (tid < 64) {
        int v = (tid < nb) ? bsum[tid] : 0;
        int x = v;
        #pragma unroll
        for (int off = 1; off < 64; off <<= 1) {
            int t = __shfl_up(x, off, 64);
            if (tid >= off) x += t;
        }
        sbo[tid] = x - v;
    }
    __syncthreads();
    int i = blockIdx.x * 256 + tid;
    if (i < e) {
        int d = dst[i];
        int rep = blockIdx.x & (REP - 1);
        int pos = rstart[d] + sbo[d >> 8] + repoff[rep * n + d] + rank[i];
        src_sorted[pos] = src[i];
    }
}

// ---------------------------------------------------------------------------
// node_mlp_v2: register-tiled GEMM chain. 32 nodes/block, 256 threads.
// ---------------------------------------------------------------------------
__global__ __launch_bounds__(256) void node_mlp_v2(
    const float* __restrict__ h,
    const float* __restrict__ W1, const float* __restrict__ b1,
    const float* __restrict__ W2, const float* __restrict__ b2,
    const float* __restrict__ v1, const float* __restrict__ attn,
    float* __restrict__ M, float* __restrict__ p, float* __restrict__ q,
    int n)
{
    __shared__ __align__(16) float hs[NT][F];
    __shared__ __align__(16) float Ts[NT][F];
    __shared__ __align__(16) float Wc[32][F];
    int tid = threadIdx.x;
    int row0 = blockIdx.x * NT;
    int j0 = (tid & 31) * 4;
    int r0 = (tid >> 5) * 4;

    #pragma unroll
    for (int it = 0; it < 4; ++it) {
        int s4 = tid + it * 256;
        int r = s4 >> 5, c4 = s4 & 31;
        int row = row0 + r;
        float4 v = make_float4(0, 0, 0, 0);
        if (row < n) v = *(const float4*)&h[(size_t)row * F + c4 * 4];
        *(float4*)&hs[r][c4 * 4] = v;
    }
    __syncthreads();

    {
        int r = tid >> 3, kp = tid & 7;
        float qa = 0.f;
        #pragma unroll
        for (int c = 0; c < 4; ++c) {
            float4 hv = *(const float4*)&hs[r][kp * 16 + c * 4];
            float4 av = *(const float4*)&attn[F + kp * 16 + c * 4];
            qa = fmaf(hv.x, av.x, qa); qa = fmaf(hv.y, av.y, qa);
            qa = fmaf(hv.z, av.z, qa); qa = fmaf(hv.w, av.w, qa);
        }
        #pragma unroll
        for (int off = 1; off < 8; off <<= 1) qa += __shfl_xor(qa, off, 64);
        int row = row0 + r;
        if (kp == 0 && row < n) q[row] = qa;
    }

    float4 acc[4];
    {
        float4 bv = *(const float4*)&b1[j0];
        #pragma unroll
        for (int i = 0; i < 4; ++i) acc[i] = bv;
    }
    for (int cc = 0; cc < 4; ++cc) {
        int kc = ((cc + (int)blockIdx.x) & 3) * 32;
        __syncthreads();
        #pragma unroll
        for (int it = 0; it < 4; ++it) {
            int s4 = tid + it * 256;
            int wr = s4 >> 5, wc4 = s4 & 31;
            *(float4*)&Wc[wr][wc4 * 4] =
                *(const float4*)&W1[(size_t)(kc + wr) * F + wc4 * 4];
        }
        __syncthreads();
        #pragma unroll
        for (int k4 = 0; k4 < 8; ++k4) {
            int kk = k4 * 4;
            float4 a0 = *(const float4*)&hs[r0 + 0][kc + kk];
            float4 a1 = *(const float4*)&hs[r0 + 1][kc + kk];
            float4 a2 = *(const float4*)&hs[r0 + 2][kc + kk];
            float4 a3 = *(const float4*)&hs[r0 + 3][kc + kk];
            #pragma unroll
            for (int k = 0; k < 4; ++k) {
                float4 b = *(const float4*)&Wc[kk + k][j0];
                float av0 = k == 0 ? a0.x : k == 1 ? a0.y : k == 2 ? a0.z : a0.w;
                float av1 = k == 0 ? a1.x : k == 1 ? a1.y : k == 2 ? a1.z : a1.w;
                float av2 = k == 0 ? a2.x : k == 1 ? a2.y : k == 2 ? a2.z : a2.w;
                float av3 = k == 0 ? a3.x : k == 1 ? a3.y : k == 2 ? a3.z : a3.w;
                acc[0].x = fmaf(av0, b.x, acc[0].x); acc[0].y = fmaf(av0, b.y, acc[0].y);
                acc[0].z = fmaf(av0, b.z, acc[0].z); acc[0].w = fmaf(av0, b.w, acc[0].w);
                acc[1].x = fmaf(av1, b.x, acc[1].x); acc[1].y = fmaf(av1, b.y, acc[1].y);
                acc[1].z = fmaf(av1, b.z, acc[1].z); acc[1].w = fmaf(av1, b.w, acc[1].w);
                acc[2].x = fmaf(av2, b.x, acc[2].x); acc[2].y = fmaf(av2, b.y, acc[2].y);
                acc[2].z = fmaf(av2, b.z, acc[2].z); acc[2].w = fmaf(av2, b.w, acc[2].w);
                acc[3].x = fmaf(av3, b.x, acc[3].x); acc[3].y = fmaf(av3, b.y, acc[3].y);
                acc[3].z = fmaf(av3, b.z, acc[3].z); acc[3].w = fmaf(av3, b.w, acc[3].w);
            }
        }
    }
    __syncthreads();
    #pragma unroll
    for (int i = 0; i < 4; ++i) {
        float4 t = acc[i];
        t.x = fmaxf(t.x, 0.f); t.y = fmaxf(t.y, 0.f);
        t.z = fmaxf(t.z, 0.f); t.w = fmaxf(t.w, 0.f);
        *(float4*)&Ts[r0 + i][j0] = t;
    }

    {
        float4 bv = *(const float4*)&b2[j0];
        #pragma unroll
        for (int i = 0; i < 4; ++i) acc[i] = bv;
    }
    for (int cc = 0; cc < 4; ++cc) {
        int kc = ((cc + (int)blockIdx.x) & 3) * 32;
        __syncthreads();
        #pragma unroll
        for (int it = 0; it < 4; ++it) {
            int s4 = tid + it * 256;
            int wr = s4 >> 5, wc4 = s4 & 31;
            *(float4*)&Wc[wr][wc4 * 4] =
                *(const float4*)&W2[(size_t)(kc + wr) * F + wc4 * 4];
        }
        __syncthreads();
        #pragma unroll
        for (int k4 = 0; k4 < 8; ++k4) {
            int kk = k4 * 4;
            float4 a0 = *(const float4*)&Ts[r0 + 0][kc + kk];
            float4 a1 = *(const float4*)&Ts[r0 + 1][kc + kk];
            float4 a2 = *(const float4*)&Ts[r0 + 2][kc + kk];
            float4 a3 = *(const float4*)&Ts[r0 + 3][kc + kk];
            #pragma unroll
            for (int k = 0; k < 4; ++k) {
                float4 b = *(const float4*)&Wc[kk + k][j0];
                float av0 = k == 0 ? a0.x : k == 1 ? a0.y : k == 2 ? a0.z : a0.w;
                float av1 = k == 0 ? a1.x : k == 1 ? a1.y : k == 2 ? a1.z : a1.w;
                float av2 = k == 0 ? a2.x : k == 1 ? a2.y : k == 2 ? a2.z : a2.w;
                float av3 = k == 0 ? a3.x : k == 1 ? a3.y : k == 2 ? a3.z : a3.w;
                acc[0].x = fmaf(av0, b.x, acc[0].x); acc[0].y = fmaf(av0, b.y, acc[0].y);
                acc[0].z = fmaf(av0, b.z, acc[0].z); acc[0].w = fmaf(av0, b.w, acc[0].w);
                acc[1].x = fmaf(av1, b.x, acc[1].x); acc[1].y = fmaf(av1, b.y, acc[1].y);
                acc[1].z = fmaf(av1, b.z, acc[1].z); acc[1].w = fmaf(av1, b.w, acc[1].w);
                acc[2].x = fmaf(av2, b.x, acc[2].x); acc[2].y = fmaf(av2, b.y, acc[2].y);
                acc[2].z = fmaf(av2, b.z, acc[2].z); acc[2].w = fmaf(av2, b.w, acc[2].w);
                acc[3].x = fmaf(av3, b.x, acc[3].x); acc[3].y = fmaf(av3, b.y, acc[3].y);
                acc[3].z = fmaf(av3, b.z, acc[3].z); acc[3].w = fmaf(av3, b.w, acc[3].w);
            }
        }
    }

    float4 v1v = *(const float4*)&v1[j0];
    #pragma unroll
    for (int i = 0; i < 4; ++i) {
        int row = row0 + r0 + i;
        if (row < n) *(float4*)&M[(size_t)row * F + j0] = acc[i];
        float pp = acc[i].x * v1v.x + acc[i].y * v1v.y +
                   acc[i].z * v1v.z + acc[i].w * v1v.w;
        #pragma unroll
        for (int off = 1; off < 32; off <<= 1) pp += __shfl_xor(pp, off, 64);
        if ((tid & 31) == 0 && row < n) p[row] = pp;
    }
}

// ---------------------------------------------------------------------------
// One WAVE per destination node: segment softmax + weighted gather.
// 16-edge batches (8 float4 loads/lane in flight); zero-weight padding.
// ---------------------------------------------------------------------------
__global__ __launch_bounds__(256) void agg_softmax_gather(
    const float* __restrict__ M, const float* __restrict__ p,
    const float* __restrict__ q, const int* __restrict__ rstart,
    const int* __restrict__ bsum, const int* __restrict__ src_sorted,
    float* __restrict__ agg, int n, int nb, int e)
{
    __shared__ int2 buf[4][DEG_CAP];
    __shared__ int sbo[64];
    int tid = threadIdx.x;
    if (tid < 64) {
        int v = (tid < nb) ? bsum[tid] : 0;
        int x = v;
        #pragma unroll
        for (int off = 1; off < 64; off <<= 1) {
            int t = __shfl_up(x, off, 64);
            if (tid >= off) x += t;
        }
        sbo[tid] = x - v;
    }
    __syncthreads();

    int lane = tid & 63;
    int wv   = tid >> 6;
    int node = blockIdx.x * 4 + wv;
    if (node >= n) return;

    int start = rstart[node] + sbo[node >> 8];
    int end   = (node + 1 < n) ? rstart[node + 1] + sbo[(node + 1) >> 8] : e;
    int deg   = end - start;
    float qn  = q[node];

    float w[KMAX];
    int   sidx[KMAX];
    float lmax = -1e30f;

    #pragma unroll
    for (int k = 0; k < KMAX; ++k) {
        int i = start + lane + (k << 6);
        bool valid = (i < end);
        int sv = valid ? src_sorted[i] : 0;
        float pv = valid ? p[sv] : 0.0f;
        float sc = pv + qn;
        float ev = (sc > 0.0f) ? sc : 0.2f * sc;
        w[k] = valid ? ev : -1e30f;
        sidx[k] = sv;
        lmax = fmaxf(lmax, w[k]);
    }
    for (int i = start + DEG_CAP + lane; i < end; i += 64) {
        float sc = p[src_sorted[i]] + qn;
        float ev = (sc > 0.0f) ? sc : 0.2f * sc;
        lmax = fmaxf(lmax, ev);
    }
    #pragma unroll
    for (int off = 32; off >= 1; off >>= 1)
        lmax = fmaxf(lmax, __shfl_xor(lmax, off, 64));

    float lsum = 0.0f;
    #pragma unroll
    for (int k = 0; k < KMAX; ++k) {
        float ex = (w[k] > -1e29f) ? __expf(w[k] - lmax) : 0.0f;
        w[k] = ex;
        lsum += ex;
    }
    for (int i = start + DEG_CAP + lane; i < end; i += 64) {
        float sc = p[src_sorted[i]] + qn;
        float ev = (sc > 0.0f) ? sc : 0.2f * sc;
        lsum += __expf(ev - lmax);
    }
    #pragma unroll
    for (int off = 32; off >= 1; off >>= 1)
        lsum += __shfl_xor(lsum, off, 64);
    float inv = 1.0f / (lsum + 1e-9f);

    #pragma unroll
    for (int k = 0; k < KMAX; ++k)
        buf[wv][lane + (k << 6)] = make_int2(__float_as_int(w[k] * inv), sidx[k]);

    const float4* M4 = (const float4*)M;
    int sub  = lane & 31;
    int half = lane >> 5;
    float accx = 0.f, accy = 0.f, accz = 0.f, accw = 0.f;
    int lim = min(deg, DEG_CAP);
    lim = (lim + 15) & ~15;              // padded slots carry weight 0

    for (int base = 0; base < lim; base += 16) {
        int2   rr[8];
        float4 mm[8];
        #pragma unroll
        for (int u = 0; u < 8; ++u) rr[u] = buf[wv][base + half + 2 * u];
        #pragma unroll
        for (int u = 0; u < 8; ++u) mm[u] = M4[(size_t)rr[u].y * 32 + sub];
        #pragma unroll
        for (int u = 0; u < 8; ++u) {
            float wu = __int_as_float(rr[u].x);
            accx = fmaf(wu, mm[u].x, accx); accy = fmaf(wu, mm[u].y, accy);
            accz = fmaf(wu, mm[u].z, accz); accw = fmaf(wu, mm[u].w, accw);
        }
    }

    for (int base = start + DEG_CAP; base < end; base += 64) {  // deg>256 only
        int i = base + lane;
        float ex = 0.f; int sv = 0;
        if (i < end) {
            sv = src_sorted[i];
            float sc = p[sv] + qn;
            float ev = (sc > 0.0f) ? sc : 0.2f * sc;
            ex = __expf(ev - lmax) * inv;
        }
        buf[wv][lane] = make_int2(__float_as_int(ex), sv);
        int cnt2 = min(64, end - base);
        for (int b2 = 0; b2 < cnt2; b2 += 2) {
            int2 r0 = buf[wv][b2 + half];
            float4 m0 = M4[(size_t)r0.y * 32 + sub];
            float w0 = __int_as_float(r0.x);
            if (b2 + half < cnt2) {
                accx = fmaf(w0, m0.x, accx); accy = fmaf(w0, m0.y, accy);
                accz = fmaf(w0, m0.z, accz); accw = fmaf(w0, m0.w, accw);
            }
        }
    }

    accx += __shfl_xor(accx, 32, 64);
    accy += __shfl_xor(accy, 32, 64);
    accz += __shfl_xor(accz, 32, 64);
    accw += __shfl_xor(accw, 32, 64);
    if (half == 0) {
        ((float4*)agg)[(size_t)node * 32 + sub] =
            make_float4(accx, accy, accz, accw);
    }
}

// ---------------------------------------------------------------------------
// update_readout_v2: register-tiled. 32 nodes/block.
// ---------------------------------------------------------------------------
__global__ __launch_bounds__(256) void update_readout_v2(
    const float* __restrict__ agg, const float* __restrict__ h,
    const float* __restrict__ Wu, const float* __restrict__ bu,
    const float* __restrict__ Wr1, const float* __restrict__ br1,
    const float* __restrict__ Wr2, const float* __restrict__ br2,
    float* __restrict__ out, int n)
{
    __shared__ __align__(16) float X[NT][2 * F];
    __shared__ __align__(16) float hn[NT][F];
    __shared__ __align__(16) float Wc[32][F];
    int tid = threadIdx.x;
    int row0 = blockIdx.x * NT;
    int j0 = (tid & 31) * 4;
    int r0 = (tid >> 5) * 4;

    #pragma unroll
    for (int it = 0; it < 8; ++it) {
        int s4 = tid + it * 256;
        int r = s4 >> 6, c4 = s4 & 63;
        int row = row0 + r;
        float4 v = make_float4(0, 0, 0, 0);
        if (row < n) {
            if (c4 < 32) v = *(const float4*)&agg[(size_t)row * F + c4 * 4];
            else         v = *(const float4*)&h[(size_t)row * F + (c4 - 32) * 4];
        }
        *(float4*)&X[r][c4 * 4] = v;
    }

    float4 acc[4];
    {
        float4 bv = *(const float4*)&bu[j0];
        #pragma unroll
        for (int i = 0; i < 4; ++i) acc[i] = bv;
    }
    for (int cc = 0; cc < 8; ++cc) {
        int kc = ((cc + (int)blockIdx.x) & 7) * 32;
        __syncthreads();
        #pragma unroll
        for (int it = 0; it < 4; ++it) {
            int s4 = tid + it * 256;
            int wr = s4 >> 5, wc4 = s4 & 31;
            *(float4*)&Wc[wr][wc4 * 4] =
                *(const float4*)&Wu[(size_t)(kc + wr) * F + wc4 * 4];
        }
        __syncthreads();
        #pragma unroll
        for (int k4 = 0; k4 < 8; ++k4) {
            int kk = k4 * 4;
            float4 a0 = *(const float4*)&X[r0 + 0][kc + kk];
            float4 a1 = *(const float4*)&X[r0 + 1][kc + kk];
            float4 a2 = *(const float4*)&X[r0 + 2][kc + kk];
            float4 a3 = *(const float4*)&X[r0 + 3][kc + kk];
            #pragma unroll
            for (int k = 0; k < 4; ++k) {
                float4 b = *(const float4*)&Wc[kk + k][j0];
                float av0 = k == 0 ? a0.x : k == 1 ? a0.y : k == 2 ? a0.z : a0.w;
                float av1 = k == 0 ? a1.x : k == 1 ? a1.y : k == 2 ? a1.z : a1.w;
                float av2 = k == 0 ? a2.x : k == 1 ? a2.y : k == 2 ? a2.z : a2.w;
                float av3 = k == 0 ? a3.x : k == 1 ? a3.y : k == 2 ? a3.z : a3.w;
                acc[0].x = fmaf(av0, b.x, acc[0].x); acc[0].y = fmaf(av0, b.y, acc[0].y);
                acc[0].z = fmaf(av0, b.z, acc[0].z); acc[0].w = fmaf(av0, b.w, acc[0].w);
                acc[1].x = fmaf(av1, b.x, acc[1].x); acc[1].y = fmaf(av1, b.y, acc[1].y);
                acc[1].z = fmaf(av1, b.z, acc[1].z); acc[1].w = fmaf(av1, b.w, acc[1].w);
                acc[2].x = fmaf(av2, b.x, acc[2].x); acc[2].y = fmaf(av2, b.y, acc[2].y);
                acc[2].z = fmaf(av2, b.z, acc[2].z); acc[2].w = fmaf(av2, b.w, acc[2].w);
                acc[3].x = fmaf(av3, b.x, acc[3].x); acc[3].y = fmaf(av3, b.y, acc[3].y);
                acc[3].z = fmaf(av3, b.z, acc[3].z); acc[3].w = fmaf(av3, b.w, acc[3].w);
            }
        }
    }
    __syncthreads();
    #pragma unroll
    for (int i = 0; i < 4; ++i) {
        float4 t = acc[i];
        t.x = fmaxf(t.x, 0.f); t.y = fmaxf(t.y, 0.f);
        t.z = fmaxf(t.z, 0.f); t.w = fmaxf(t.w, 0.f);
        *(float4*)&hn[r0 + i][j0] = t;
    }

    int h0 = (tid & 31) * 2;
    float r1[4][2];
    {
        float b0 = br1[h0], b1v = br1[h0 + 1];
        #pragma unroll
        for (int i = 0; i < 4; ++i) { r1[i][0] = b0; r1[i][1] = b1v; }
    }
    float* Wcr = &Wc[0][0];
    for (int cc = 0; cc < 2; ++cc) {
        int kc = cc * 64;
        __syncthreads();
        #pragma unroll
        for (int it = 0; it < 4; ++it) {
            int s4 = tid + it * 256;
            int wr = s4 >> 4, wc4 = s4 & 15;
            *(float4*)&Wcr[wr * 64 + wc4 * 4] =
                *(const float4*)&Wr1[(size_t)(kc + wr) * HID + wc4 * 4];
        }
        __syncthreads();
        #pragma unroll
        for (int k4 = 0; k4 < 16; ++k4) {
            int kk = k4 * 4;
            float4 a0 = *(const float4*)&hn[r0 + 0][kc + kk];
            float4 a1 = *(const float4*)&hn[r0 + 1][kc + kk];
            float4 a2 = *(const float4*)&hn[r0 + 2][kc + kk];
            float4 a3 = *(const float4*)&hn[r0 + 3][kc + kk];
            #pragma unroll
            for (int k = 0; k < 4; ++k) {
                float2 b = *(const float2*)&Wcr[(kk + k) * 64 + h0];
                float av0 = k == 0 ? a0.x : k == 1 ? a0.y : k == 2 ? a0.z : a0.w;
                float av1 = k == 0 ? a1.x : k == 1 ? a1.y : k == 2 ? a1.z : a1.w;
                float av2 = k == 0 ? a2.x : k == 1 ? a2.y : k == 2 ? a2.z : a2.w;
                float av3 = k == 0 ? a3.x : k == 1 ? a3.y : k == 2 ? a3.z : a3.w;
                r1[0][0] = fmaf(av0, b.x, r1[0][0]); r1[0][1] = fmaf(av0, b.y, r1[0][1]);
                r1[1][0] = fmaf(av1, b.x, r1[1][0]); r1[1][1] = fmaf(av1, b.y, r1[1][1]);
                r1[2][0] = fmaf(av2, b.x, r1[2][0]); r1[2][1] = fmaf(av2, b.y, r1[2][1]);
                r1[3][0] = fmaf(av3, b.x, r1[3][0]); r1[3][1] = fmaf(av3, b.y, r1[3][1]);
            }
        }
    }

    float wa = Wr2[h0], wb = Wr2[h0 + 1];
    float b2v = br2[0];
    #pragma unroll
    for (int i = 0; i < 4; ++i) {
        float s = fmaxf(r1[i][0], 0.f) * wa + fmaxf(r1[i][1], 0.f) * wb;
        #pragma unroll
        for (int off = 1; off < 32; off <<= 1) s += __shfl_xor(s, off, 64);
        int row = row0 + r0 + i;
        if ((tid & 31) == 0 && row < n) out[row] = s + b2v;
    }
}

// ---------------------------------------------------------------------------
extern "C" void kernel_launch(void* const* d_in, const int* in_sizes, int n_in,
                              void* d_out, int out_size, void* d_ws, size_t ws_size,
                              hipStream_t stream) {
    const float* h    = (const float*)d_in[0];
    const int*   src  = (const int*)d_in[1];
    const int*   dst  = (const int*)d_in[2];
    const float* W1   = (const float*)d_in[3];
    const float* b1   = (const float*)d_in[4];
    const float* W2   = (const float*)d_in[5];
    const float* b2   = (const float*)d_in[6];
    const float* nk   = (const float*)d_in[7];
    const float* attn = (const float*)d_in[8];
    const float* Wu   = (const float*)d_in[9];
    const float* bu   = (const float*)d_in[10];
    const float* Wr1  = (const float*)d_in[11];
    const float* br1  = (const float*)d_in[12];
    const float* Wr2  = (const float*)d_in[13];
    const float* br2  = (const float*)d_in[14];
    float* out = (float*)d_out;

    int n = in_sizes[0] / F;    // 10000
    int e = in_sizes[1];        // 640000
    int nb = (n + 255) / 256;   // 40

    char* ws = (char*)d_ws;
    size_t off = 0;
    auto alloc = [&](size_t bytes) {
        void* pp = ws + off;
        off += (bytes + 511) & ~(size_t)511;
        return pp;
    };
    float* M       = (float*)alloc((size_t)n * F * 4);
    float* aggws   = (float*)alloc((size_t)n * F * 4);
    float* p       = (float*)alloc((size_t)n * 4);
    float* q       = (float*)alloc((size_t)n * 4);
    float* v1      = (float*)alloc(F * 4);
    int*   cnt     = (int*)alloc((size_t)REP * n * 4);
    int*   repoff  = (int*)alloc((size_t)REP * n * 4);
    int*   rstart  = (int*)alloc((size_t)(n + 1) * 4);
    int*   bsum    = (int*)alloc((size_t)(nb + 1) * 4);
    int*   rank    = (int*)alloc((size_t)e * 4);
    int*   srcsort = (int*)alloc((size_t)e * 4);

    hipMemsetAsync(cnt, 0, (size_t)REP * n * 4, stream);
    hist_rank<<<(e + 255) / 256, 256, 0, stream>>>(dst, cnt, rank, e, n,
                                                   nk, attn, v1);
    scan_block<<<nb, 256, 0, stream>>>(cnt, repoff, rstart, bsum, n);
    fill_kernel<<<(e + 255) / 256, 256, 0, stream>>>(dst, src, rank, rstart,
                                                     repoff, bsum, srcsort,
                                                     n, nb, e);
    node_mlp_v2<<<(n + NT - 1) / NT, 256, 0, stream>>>(h, W1, b1, W2, b2, v1,
                                                       attn, M, p, q, n);
    agg_softmax_gather<<<(n + 3) / 4, 256, 0, stream>>>(M, p, q, rstart, bsum,
                                                        srcsort, aggws, n, nb, e);
    update_readout_v2<<<(n + NT - 1) / NT, 256, 0, stream>>>(aggws, h, Wu, bu,
                                                             Wr1, br1, Wr2, br2,
                                                             out, n);
}

// Round 7
// 201.246 us; speedup vs baseline: 1.7884x; 1.0543x over previous
//
#include <hip/hip_runtime.h>
#include <hip/hip_bf16.h>
#include <hip/hip_fp16.h>

#define F 128
#define HID 64
#define KMAX 4
#define DEG_CAP 256   // KMAX * 64
#define NT 32         // nodes per block in dense kernels
#define REP 8         // histogram replicas

// ---------------------------------------------------------------------------
// fused_front: blocks [0, histBlocks) do the replicated histogram + rank;
// blocks [histBlocks, histBlocks+mlpBlocks) run the node message MLP
// (register-tiled, Ts aliased onto hs, per-block v1 recompute).
// Outputs: cnt/rank (hist), Mh (fp16 messages), p, q.
// ---------------------------------------------------------------------------
__global__ __launch_bounds__(256) void fused_front(
    const int* __restrict__ dst, int* cnt, int* __restrict__ rank, int e,
    int n, int histBlocks,
    const float* __restrict__ h,
    const float* __restrict__ W1, const float* __restrict__ b1,
    const float* __restrict__ W2, const float* __restrict__ b2,
    const float* __restrict__ nk, const float* __restrict__ attn,
    __half* __restrict__ Mh, float* __restrict__ p, float* __restrict__ q)
{
    int tid = threadIdx.x;

    if ((int)blockIdx.x < histBlocks) {
        int i = blockIdx.x * 256 + tid;
        int rep = blockIdx.x & (REP - 1);
        if (i < e) rank[i] = atomicAdd(&cnt[rep * n + dst[i]], 1);
        return;
    }

    // ---------------- node MLP part ----------------
    __shared__ __align__(16) float hsTs[NT][F];   // h, then relu(h@W1+b1)
    __shared__ __align__(16) float Wc[32][F];     // weight chunk
    __shared__ __align__(16) float v1s[F];
    int bm = blockIdx.x - histBlocks;
    int row0 = bm * NT;
    int j0 = (tid & 31) * 4;
    int r0 = (tid >> 5) * 4;

    // stage h tile
    #pragma unroll
    for (int it = 0; it < 4; ++it) {
        int s4 = tid + it * 256;
        int r = s4 >> 5, c4 = s4 & 31;
        int row = row0 + r;
        float4 v = make_float4(0, 0, 0, 0);
        if (row < n) v = *(const float4*)&h[(size_t)row * F + c4 * 4];
        *(float4*)&hsTs[r][c4 * 4] = v;
    }
    // per-block v1 = node_kernel @ attn[:F]
    if (tid < F) {
        float a = 0.f;
        const float4* nkr = (const float4*)&nk[(size_t)tid * F];
        const float4* at4 = (const float4*)attn;
        #pragma unroll 8
        for (int j = 0; j < 32; ++j) {
            float4 nv = nkr[j]; float4 av = at4[j];
            a = fmaf(nv.x, av.x, a); a = fmaf(nv.y, av.y, a);
            a = fmaf(nv.z, av.z, a); a = fmaf(nv.w, av.w, a);
        }
        v1s[tid] = a;
    }
    __syncthreads();

    // q = h . attn[F:]
    {
        int r = tid >> 3, kp = tid & 7;
        float qa = 0.f;
        #pragma unroll
        for (int c = 0; c < 4; ++c) {
            float4 hv = *(const float4*)&hsTs[r][kp * 16 + c * 4];
            float4 av = *(const float4*)&attn[F + kp * 16 + c * 4];
            qa = fmaf(hv.x, av.x, qa); qa = fmaf(hv.y, av.y, qa);
            qa = fmaf(hv.z, av.z, qa); qa = fmaf(hv.w, av.w, qa);
        }
        #pragma unroll
        for (int off = 1; off < 8; off <<= 1) qa += __shfl_xor(qa, off, 64);
        int row = row0 + r;
        if (kp == 0 && row < n) q[row] = qa;
    }

    float4 acc[4];
    // layer 1: T = relu(h @ W1 + b1)
    {
        float4 bv = *(const float4*)&b1[j0];
        #pragma unroll
        for (int i = 0; i < 4; ++i) acc[i] = bv;
    }
    for (int cc = 0; cc < 4; ++cc) {
        int kc = ((cc + bm) & 3) * 32;
        __syncthreads();
        #pragma unroll
        for (int it = 0; it < 4; ++it) {
            int s4 = tid + it * 256;
            int wr = s4 >> 5, wc4 = s4 & 31;
            *(float4*)&Wc[wr][wc4 * 4] =
                *(const float4*)&W1[(size_t)(kc + wr) * F + wc4 * 4];
        }
        __syncthreads();
        #pragma unroll
        for (int k4 = 0; k4 < 8; ++k4) {
            int kk = k4 * 4;
            float4 a0 = *(const float4*)&hsTs[r0 + 0][kc + kk];
            float4 a1 = *(const float4*)&hsTs[r0 + 1][kc + kk];
            float4 a2 = *(const float4*)&hsTs[r0 + 2][kc + kk];
            float4 a3 = *(const float4*)&hsTs[r0 + 3][kc + kk];
            #pragma unroll
            for (int k = 0; k < 4; ++k) {
                float4 b = *(const float4*)&Wc[kk + k][j0];
                float av0 = k == 0 ? a0.x : k == 1 ? a0.y : k == 2 ? a0.z : a0.w;
                float av1 = k == 0 ? a1.x : k == 1 ? a1.y : k == 2 ? a1.z : a1.w;
                float av2 = k == 0 ? a2.x : k == 1 ? a2.y : k == 2 ? a2.z : a2.w;
                float av3 = k == 0 ? a3.x : k == 1 ? a3.y : k == 2 ? a3.z : a3.w;
                acc[0].x = fmaf(av0, b.x, acc[0].x); acc[0].y = fmaf(av0, b.y, acc[0].y);
                acc[0].z = fmaf(av0, b.z, acc[0].z); acc[0].w = fmaf(av0, b.w, acc[0].w);
                acc[1].x = fmaf(av1, b.x, acc[1].x); acc[1].y = fmaf(av1, b.y, acc[1].y);
                acc[1].z = fmaf(av1, b.z, acc[1].z); acc[1].w = fmaf(av1, b.w, acc[1].w);
                acc[2].x = fmaf(av2, b.x, acc[2].x); acc[2].y = fmaf(av2, b.y, acc[2].y);
                acc[2].z = fmaf(av2, b.z, acc[2].z); acc[2].w = fmaf(av2, b.w, acc[2].w);
                acc[3].x = fmaf(av3, b.x, acc[3].x); acc[3].y = fmaf(av3, b.y, acc[3].y);
                acc[3].z = fmaf(av3, b.z, acc[3].z); acc[3].w = fmaf(av3, b.w, acc[3].w);
            }
        }
    }
    __syncthreads();   // all layer-1 reads of hsTs done
    #pragma unroll
    for (int i = 0; i < 4; ++i) {
        float4 t = acc[i];
        t.x = fmaxf(t.x, 0.f); t.y = fmaxf(t.y, 0.f);
        t.z = fmaxf(t.z, 0.f); t.w = fmaxf(t.w, 0.f);
        *(float4*)&hsTs[r0 + i][j0] = t;      // overwrite with T
    }

    // layer 2: M = T @ W2 + b2
    {
        float4 bv = *(const float4*)&b2[j0];
        #pragma unroll
        for (int i = 0; i < 4; ++i) acc[i] = bv;
    }
    for (int cc = 0; cc < 4; ++cc) {
        int kc = ((cc + bm) & 3) * 32;
        __syncthreads();
        #pragma unroll
        for (int it = 0; it < 4; ++it) {
            int s4 = tid + it * 256;
            int wr = s4 >> 5, wc4 = s4 & 31;
            *(float4*)&Wc[wr][wc4 * 4] =
                *(const float4*)&W2[(size_t)(kc + wr) * F + wc4 * 4];
        }
        __syncthreads();
        #pragma unroll
        for (int k4 = 0; k4 < 8; ++k4) {
            int kk = k4 * 4;
            float4 a0 = *(const float4*)&hsTs[r0 + 0][kc + kk];
            float4 a1 = *(const float4*)&hsTs[r0 + 1][kc + kk];
            float4 a2 = *(const float4*)&hsTs[r0 + 2][kc + kk];
            float4 a3 = *(const float4*)&hsTs[r0 + 3][kc + kk];
            #pragma unroll
            for (int k = 0; k < 4; ++k) {
                float4 b = *(const float4*)&Wc[kk + k][j0];
                float av0 = k == 0 ? a0.x : k == 1 ? a0.y : k == 2 ? a0.z : a0.w;
                float av1 = k == 0 ? a1.x : k == 1 ? a1.y : k == 2 ? a1.z : a1.w;
                float av2 = k == 0 ? a2.x : k == 1 ? a2.y : k == 2 ? a2.z : a2.w;
                float av3 = k == 0 ? a3.x : k == 1 ? a3.y : k == 2 ? a3.z : a3.w;
                acc[0].x = fmaf(av0, b.x, acc[0].x); acc[0].y = fmaf(av0, b.y, acc[0].y);
                acc[0].z = fmaf(av0, b.z, acc[0].z); acc[0].w = fmaf(av0, b.w, acc[0].w);
                acc[1].x = fmaf(av1, b.x, acc[1].x); acc[1].y = fmaf(av1, b.y, acc[1].y);
                acc[1].z = fmaf(av1, b.z, acc[1].z); acc[1].w = fmaf(av1, b.w, acc[1].w);
                acc[2].x = fmaf(av2, b.x, acc[2].x); acc[2].y = fmaf(av2, b.y, acc[2].y);
                acc[2].z = fmaf(av2, b.z, acc[2].z); acc[2].w = fmaf(av2, b.w, acc[2].w);
                acc[3].x = fmaf(av3, b.x, acc[3].x); acc[3].y = fmaf(av3, b.y, acc[3].y);
                acc[3].z = fmaf(av3, b.z, acc[3].z); acc[3].w = fmaf(av3, b.w, acc[3].w);
            }
        }
    }

    // store Mh (fp16) + p = M.v1 (from fp32 accumulators)
    float4 v1v = *(const float4*)&v1s[j0];
    #pragma unroll
    for (int i = 0; i < 4; ++i) {
        int row = row0 + r0 + i;
        if (row < n) {
            __half hv[4];
            hv[0] = __float2half(acc[i].x); hv[1] = __float2half(acc[i].y);
            hv[2] = __float2half(acc[i].z); hv[3] = __float2half(acc[i].w);
            *(uint2*)&Mh[(size_t)row * F + j0] = *(uint2*)hv;
        }
        float pp = acc[i].x * v1v.x + acc[i].y * v1v.y +
                   acc[i].z * v1v.z + acc[i].w * v1v.w;
        #pragma unroll
        for (int off = 1; off < 32; off <<= 1) pp += __shfl_xor(pp, off, 64);
        if ((tid & 31) == 0 && row < n) p[row] = pp;
    }
}

// ---------------------------------------------------------------------------
// scan_block: replica fold (repoff) + per-block exclusive scan of totals.
// rstart stays PARTIAL; consumers add the top-level offset from bsum inline.
// ---------------------------------------------------------------------------
__global__ __launch_bounds__(256) void scan_block(
    const int* __restrict__ cnt, int* __restrict__ repoff,
    int* __restrict__ rstart, int* __restrict__ bsum, int n)
{
    int tid = threadIdx.x;
    int i = blockIdx.x * 256 + tid;
    int v = 0;
    if (i < n) {
        int run = 0;
        #pragma unroll
        for (int r = 0; r < REP; ++r) {
            int c = cnt[r * n + i];
            repoff[r * n + i] = run;
            run += c;
        }
        v = run;
    }
    int lane = tid & 63, wv = tid >> 6;
    int x = v;
    #pragma unroll
    for (int off = 1; off < 64; off <<= 1) {
        int t = __shfl_up(x, off, 64);
        if (lane >= off) x += t;
    }
    __shared__ int wsum[4];
    if (lane == 63) wsum[wv] = x;
    __syncthreads();
    int woff = 0;
    #pragma unroll
    for (int wdx = 0; wdx < 4; ++wdx) woff += (wdx < wv) ? wsum[wdx] : 0;
    int incl = x + woff;
    if (i < n) rstart[i] = incl - v;
    if (tid == 255) bsum[blockIdx.x] = incl;
}

// ---------------------------------------------------------------------------
// fill: atomic-free scatter; top-level bsum scan recomputed inline in LDS.
// ---------------------------------------------------------------------------
__global__ __launch_bounds__(256) void fill_kernel(
    const int* __restrict__ dst, const int* __restrict__ src,
    const int* __restrict__ rank, const int* __restrict__ rstart,
    const int* __restrict__ repoff, const int* __restrict__ bsum,
    int* __restrict__ src_sorted, int n, int nb, int e)
{
    __shared__ int sbo[64];
    int tid = threadIdx.x;
    if (tid < 64) {
        int v = (tid < nb) ? bsum[tid] : 0;
        int x = v;
        #pragma unroll
        for (int off = 1; off < 64; off <<= 1) {
            int t = __shfl_up(x, off, 64);
            if (tid >= off) x += t;
        }
        sbo[tid] = x - v;
    }
    __syncthreads();
    int i = blockIdx.x * 256 + tid;
    if (i < e) {
        int d = dst[i];
        int rep = blockIdx.x & (REP - 1);
        int pos = rstart[d] + sbo[d >> 8] + repoff[rep * n + d] + rank[i];
        src_sorted[pos] = src[i];
    }
}

// ---------------------------------------------------------------------------
// One WAVE per destination node: segment softmax + weighted fp16 gather.
// Quarter-wave (16 lanes x 16B) covers one 256B Mh row -> 4 edges per load
// instruction, 4 loads per lane in flight per batch of 16 edges.
// ---------------------------------------------------------------------------
__global__ __launch_bounds__(256) void agg_softmax_gather(
    const __half* __restrict__ Mh, const float* __restrict__ p,
    const float* __restrict__ q, const int* __restrict__ rstart,
    const int* __restrict__ bsum, const int* __restrict__ src_sorted,
    float* __restrict__ agg, int n, int nb, int e)
{
    __shared__ int2 buf[4][DEG_CAP];
    __shared__ int sbo[64];
    int tid = threadIdx.x;
    if (tid < 64) {
        int v = (tid < nb) ? bsum[tid] : 0;
        int x = v;
        #pragma unroll
        for (int off = 1; off < 64; off <<= 1) {
            int t = __shfl_up(x, off, 64);
            if (tid >= off) x += t;
        }
        sbo[tid] = x - v;
    }
    __syncthreads();

    int lane = tid & 63;
    int wv   = tid >> 6;
    int node = blockIdx.x * 4 + wv;
    if (node >= n) return;

    int start = rstart[node] + sbo[node >> 8];
    int end   = (node + 1 < n) ? rstart[node + 1] + sbo[(node + 1) >> 8] : e;
    int deg   = end - start;
    float qn  = q[node];

    float w[KMAX];
    int   sidx[KMAX];
    float lmax = -1e30f;

    #pragma unroll
    for (int k = 0; k < KMAX; ++k) {
        int i = start + lane + (k << 6);
        bool valid = (i < end);
        int sv = valid ? src_sorted[i] : 0;
        float pv = valid ? p[sv] : 0.0f;
        float sc = pv + qn;
        float ev = (sc > 0.0f) ? sc : 0.2f * sc;
        w[k] = valid ? ev : -1e30f;
        sidx[k] = sv;
        lmax = fmaxf(lmax, w[k]);
    }
    for (int i = start + DEG_CAP + lane; i < end; i += 64) {
        float sc = p[src_sorted[i]] + qn;
        float ev = (sc > 0.0f) ? sc : 0.2f * sc;
        lmax = fmaxf(lmax, ev);
    }
    #pragma unroll
    for (int off = 32; off >= 1; off >>= 1)
        lmax = fmaxf(lmax, __shfl_xor(lmax, off, 64));

    float lsum = 0.0f;
    #pragma unroll
    for (int k = 0; k < KMAX; ++k) {
        float ex = (w[k] > -1e29f) ? __expf(w[k] - lmax) : 0.0f;
        w[k] = ex;
        lsum += ex;
    }
    for (int i = start + DEG_CAP + lane; i < end; i += 64) {
        float sc = p[src_sorted[i]] + qn;
        float ev = (sc > 0.0f) ? sc : 0.2f * sc;
        lsum += __expf(ev - lmax);
    }
    #pragma unroll
    for (int off = 32; off >= 1; off >>= 1)
        lsum += __shfl_xor(lsum, off, 64);
    float inv = 1.0f / (lsum + 1e-9f);

    #pragma unroll
    for (int k = 0; k < KMAX; ++k)
        buf[wv][lane + (k << 6)] = make_int2(__float_as_int(w[k] * inv), sidx[k]);

    const uint4* M16 = (const uint4*)Mh;   // 16B = 8 halfs; row = 16 uint4
    int sub16 = lane & 15;
    int quar  = lane >> 4;
    float acc[8] = {0.f, 0.f, 0.f, 0.f, 0.f, 0.f, 0.f, 0.f};
    int lim = min(deg, DEG_CAP);
    lim = (lim + 15) & ~15;              // padded slots carry weight 0

    for (int base = 0; base < lim; base += 16) {
        int2  rr[4];
        uint4 mm[4];
        #pragma unroll
        for (int u = 0; u < 4; ++u) rr[u] = buf[wv][base + quar + 4 * u];
        #pragma unroll
        for (int u = 0; u < 4; ++u) mm[u] = M16[(size_t)rr[u].y * 16 + sub16];
        #pragma unroll
        for (int u = 0; u < 4; ++u) {
            float wu = __int_as_float(rr[u].x);
            const __half2* hp = (const __half2*)&mm[u];
            float2 f0 = __half22float2(hp[0]);
            float2 f1 = __half22float2(hp[1]);
            float2 f2 = __half22float2(hp[2]);
            float2 f3 = __half22float2(hp[3]);
            acc[0] = fmaf(wu, f0.x, acc[0]); acc[1] = fmaf(wu, f0.y, acc[1]);
            acc[2] = fmaf(wu, f1.x, acc[2]); acc[3] = fmaf(wu, f1.y, acc[3]);
            acc[4] = fmaf(wu, f2.x, acc[4]); acc[5] = fmaf(wu, f2.y, acc[5]);
            acc[6] = fmaf(wu, f3.x, acc[6]); acc[7] = fmaf(wu, f3.y, acc[7]);
        }
    }

    // overflow path (deg > 256): correctness-only
    for (int base = start + DEG_CAP; base < end; base += 64) {
        int i = base + lane;
        float ex = 0.f; int sv = 0;
        if (i < end) {
            sv = src_sorted[i];
            float sc = p[sv] + qn;
            float ev = (sc > 0.0f) ? sc : 0.2f * sc;
            ex = __expf(ev - lmax) * inv;
        }
        buf[wv][lane] = make_int2(__float_as_int(ex), sv);
        for (int b2 = 0; b2 < 64; b2 += 4) {
            int2 rr = buf[wv][b2 + quar];
            uint4 mm = M16[(size_t)rr.y * 16 + sub16];
            float wu = __int_as_float(rr.x);
            const __half2* hp = (const __half2*)&mm;
            float2 f0 = __half22float2(hp[0]);
            float2 f1 = __half22float2(hp[1]);
            float2 f2 = __half22float2(hp[2]);
            float2 f3 = __half22float2(hp[3]);
            acc[0] = fmaf(wu, f0.x, acc[0]); acc[1] = fmaf(wu, f0.y, acc[1]);
            acc[2] = fmaf(wu, f1.x, acc[2]); acc[3] = fmaf(wu, f1.y, acc[3]);
            acc[4] = fmaf(wu, f2.x, acc[4]); acc[5] = fmaf(wu, f2.y, acc[5]);
            acc[6] = fmaf(wu, f3.x, acc[6]); acc[7] = fmaf(wu, f3.y, acc[7]);
        }
    }

    // combine the 4 quarter-waves (stride-16 butterfly), then store
    #pragma unroll
    for (int j = 0; j < 8; ++j) {
        acc[j] += __shfl_xor(acc[j], 16, 64);
        acc[j] += __shfl_xor(acc[j], 32, 64);
    }
    if (quar == 0) {
        float* dst0 = &agg[(size_t)node * F + sub16 * 8];
        *(float4*)dst0       = make_float4(acc[0], acc[1], acc[2], acc[3]);
        *(float4*)(dst0 + 4) = make_float4(acc[4], acc[5], acc[6], acc[7]);
    }
}

// ---------------------------------------------------------------------------
// update_readout_v2: register-tiled. 32 nodes/block.
// ---------------------------------------------------------------------------
__global__ __launch_bounds__(256) void update_readout_v2(
    const float* __restrict__ agg, const float* __restrict__ h,
    const float* __restrict__ Wu, const float* __restrict__ bu,
    const float* __restrict__ Wr1, const float* __restrict__ br1,
    const float* __restrict__ Wr2, const float* __restrict__ br2,
    float* __restrict__ out, int n)
{
    __shared__ __align__(16) float X[NT][2 * F];
    __shared__ __align__(16) float hn[NT][F];
    __shared__ __align__(16) float Wc[32][F];
    int tid = threadIdx.x;
    int row0 = blockIdx.x * NT;
    int j0 = (tid & 31) * 4;
    int r0 = (tid >> 5) * 4;

    #pragma unroll
    for (int it = 0; it < 8; ++it) {
        int s4 = tid + it * 256;
        int r = s4 >> 6, c4 = s4 & 63;
        int row = row0 + r;
        float4 v = make_float4(0, 0, 0, 0);
        if (row < n) {
            if (c4 < 32) v = *(const float4*)&agg[(size_t)row * F + c4 * 4];
            else         v = *(const float4*)&h[(size_t)row * F + (c4 - 32) * 4];
        }
        *(float4*)&X[r][c4 * 4] = v;
    }

    float4 acc[4];
    {
        float4 bv = *(const float4*)&bu[j0];
        #pragma unroll
        for (int i = 0; i < 4; ++i) acc[i] = bv;
    }
    for (int cc = 0; cc < 8; ++cc) {
        int kc = ((cc + (int)blockIdx.x) & 7) * 32;
        __syncthreads();
        #pragma unroll
        for (int it = 0; it < 4; ++it) {
            int s4 = tid + it * 256;
            int wr = s4 >> 5, wc4 = s4 & 31;
            *(float4*)&Wc[wr][wc4 * 4] =
                *(const float4*)&Wu[(size_t)(kc + wr) * F + wc4 * 4];
        }
        __syncthreads();
        #pragma unroll
        for (int k4 = 0; k4 < 8; ++k4) {
            int kk = k4 * 4;
            float4 a0 = *(const float4*)&X[r0 + 0][kc + kk];
            float4 a1 = *(const float4*)&X[r0 + 1][kc + kk];
            float4 a2 = *(const float4*)&X[r0 + 2][kc + kk];
            float4 a3 = *(const float4*)&X[r0 + 3][kc + kk];
            #pragma unroll
            for (int k = 0; k < 4; ++k) {
                float4 b = *(const float4*)&Wc[kk + k][j0];
                float av0 = k == 0 ? a0.x : k == 1 ? a0.y : k == 2 ? a0.z : a0.w;
                float av1 = k == 0 ? a1.x : k == 1 ? a1.y : k == 2 ? a1.z : a1.w;
                float av2 = k == 0 ? a2.x : k == 1 ? a2.y : k == 2 ? a2.z : a2.w;
                float av3 = k == 0 ? a3.x : k == 1 ? a3.y : k == 2 ? a3.z : a3.w;
                acc[0].x = fmaf(av0, b.x, acc[0].x); acc[0].y = fmaf(av0, b.y, acc[0].y);
                acc[0].z = fmaf(av0, b.z, acc[0].z); acc[0].w = fmaf(av0, b.w, acc[0].w);
                acc[1].x = fmaf(av1, b.x, acc[1].x); acc[1].y = fmaf(av1, b.y, acc[1].y);
                acc[1].z = fmaf(av1, b.z, acc[1].z); acc[1].w = fmaf(av1, b.w, acc[1].w);
                acc[2].x = fmaf(av2, b.x, acc[2].x); acc[2].y = fmaf(av2, b.y, acc[2].y);
                acc[2].z = fmaf(av2, b.z, acc[2].z); acc[2].w = fmaf(av2, b.w, acc[2].w);
                acc[3].x = fmaf(av3, b.x, acc[3].x); acc[3].y = fmaf(av3, b.y, acc[3].y);
                acc[3].z = fmaf(av3, b.z, acc[3].z); acc[3].w = fmaf(av3, b.w, acc[3].w);
            }
        }
    }
    __syncthreads();
    #pragma unroll
    for (int i = 0; i < 4; ++i) {
        float4 t = acc[i];
        t.x = fmaxf(t.x, 0.f); t.y = fmaxf(t.y, 0.f);
        t.z = fmaxf(t.z, 0.f); t.w = fmaxf(t.w, 0.f);
        *(float4*)&hn[r0 + i][j0] = t;
    }

    int h0 = (tid & 31) * 2;
    float r1[4][2];
    {
        float b0 = br1[h0], b1v = br1[h0 + 1];
        #pragma unroll
        for (int i = 0; i < 4; ++i) { r1[i][0] = b0; r1[i][1] = b1v; }
    }
    float* Wcr = &Wc[0][0];
    for (int cc = 0; cc < 2; ++cc) {
        int kc = cc * 64;
        __syncthreads();
        #pragma unroll
        for (int it = 0; it < 4; ++it) {
            int s4 = tid + it * 256;
            int wr = s4 >> 4, wc4 = s4 & 15;
            *(float4*)&Wcr[wr * 64 + wc4 * 4] =
                *(const float4*)&Wr1[(size_t)(kc + wr) * HID + wc4 * 4];
        }
        __syncthreads();
        #pragma unroll
        for (int k4 = 0; k4 < 16; ++k4) {
            int kk = k4 * 4;
            float4 a0 = *(const float4*)&hn[r0 + 0][kc + kk];
            float4 a1 = *(const float4*)&hn[r0 + 1][kc + kk];
            float4 a2 = *(const float4*)&hn[r0 + 2][kc + kk];
            float4 a3 = *(const float4*)&hn[r0 + 3][kc + kk];
            #pragma unroll
            for (int k = 0; k < 4; ++k) {
                float2 b = *(const float2*)&Wcr[(kk + k) * 64 + h0];
                float av0 = k == 0 ? a0.x : k == 1 ? a0.y : k == 2 ? a0.z : a0.w;
                float av1 = k == 0 ? a1.x : k == 1 ? a1.y : k == 2 ? a1.z : a1.w;
                float av2 = k == 0 ? a2.x : k == 1 ? a2.y : k == 2 ? a2.z : a2.w;
                float av3 = k == 0 ? a3.x : k == 1 ? a3.y : k == 2 ? a3.z : a3.w;
                r1[0][0] = fmaf(av0, b.x, r1[0][0]); r1[0][1] = fmaf(av0, b.y, r1[0][1]);
                r1[1][0] = fmaf(av1, b.x, r1[1][0]); r1[1][1] = fmaf(av1, b.y, r1[1][1]);
                r1[2][0] = fmaf(av2, b.x, r1[2][0]); r1[2][1] = fmaf(av2, b.y, r1[2][1]);
                r1[3][0] = fmaf(av3, b.x, r1[3][0]); r1[3][1] = fmaf(av3, b.y, r1[3][1]);
            }
        }
    }

    float wa = Wr2[h0], wb = Wr2[h0 + 1];
    float b2v = br2[0];
    #pragma unroll
    for (int i = 0; i < 4; ++i) {
        float s = fmaxf(r1[i][0], 0.f) * wa + fmaxf(r1[i][1], 0.f) * wb;
        #pragma unroll
        for (int off = 1; off < 32; off <<= 1) s += __shfl_xor(s, off, 64);
        int row = row0 + r0 + i;
        if ((tid & 31) == 0 && row < n) out[row] = s + b2v;
    }
}

// ---------------------------------------------------------------------------
extern "C" void kernel_launch(void* const* d_in, const int* in_sizes, int n_in,
                              void* d_out, int out_size, void* d_ws, size_t ws_size,
                              hipStream_t stream) {
    const float* h    = (const float*)d_in[0];
    const int*   src  = (const int*)d_in[1];
    const int*   dst  = (const int*)d_in[2];
    const float* W1   = (const float*)d_in[3];
    const float* b1   = (const float*)d_in[4];
    const float* W2   = (const float*)d_in[5];
    const float* b2   = (const float*)d_in[6];
    const float* nk   = (const float*)d_in[7];
    const float* attn = (const float*)d_in[8];
    const float* Wu   = (const float*)d_in[9];
    const float* bu   = (const float*)d_in[10];
    const float* Wr1  = (const float*)d_in[11];
    const float* br1  = (const float*)d_in[12];
    const float* Wr2  = (const float*)d_in[13];
    const float* br2  = (const float*)d_in[14];
    float* out = (float*)d_out;

    int n = in_sizes[0] / F;    // 10000
    int e = in_sizes[1];        // 640000
    int nb = (n + 255) / 256;   // 40
    int histBlocks = (e + 255) / 256;       // 2500
    int mlpBlocks  = (n + NT - 1) / NT;     // 313

    char* ws = (char*)d_ws;
    size_t off = 0;
    auto alloc = [&](size_t bytes) {
        void* pp = ws + off;
        off += (bytes + 511) & ~(size_t)511;
        return pp;
    };
    __half* Mh     = (__half*)alloc((size_t)n * F * 2);
    float* aggws   = (float*)alloc((size_t)n * F * 4);
    float* p       = (float*)alloc((size_t)n * 4);
    float* q       = (float*)alloc((size_t)n * 4);
    int*   cnt     = (int*)alloc((size_t)REP * n * 4);
    int*   repoff  = (int*)alloc((size_t)REP * n * 4);
    int*   rstart  = (int*)alloc((size_t)(n + 1) * 4);
    int*   bsum    = (int*)alloc((size_t)(nb + 1) * 4);
    int*   rank    = (int*)alloc((size_t)e * 4);
    int*   srcsort = (int*)alloc((size_t)e * 4);

    hipMemsetAsync(cnt, 0, (size_t)REP * n * 4, stream);
    fused_front<<<histBlocks + mlpBlocks, 256, 0, stream>>>(
        dst, cnt, rank, e, n, histBlocks,
        h, W1, b1, W2, b2, nk, attn, Mh, p, q);
    scan_block<<<nb, 256, 0, stream>>>(cnt, repoff, rstart, bsum, n);
    fill_kernel<<<histBlocks, 256, 0, stream>>>(dst, src, rank, rstart,
                                                repoff, bsum, srcsort,
                                                n, nb, e);
    agg_softmax_gather<<<(n + 3) / 4, 256, 0, stream>>>(Mh, p, q, rstart, bsum,
                                                        srcsort, aggws, n, nb, e);
    update_readout_v2<<<mlpBlocks, 256, 0, stream>>>(aggws, h, Wu, bu,
                                                     Wr1, br1, Wr2, br2,
                                                     out, n);
}